// Round 9
// baseline (467.704 us; speedup 1.0000x reference)
//
#include <hip/hip_runtime.h>

#define B_ 2
#define N_ 16384
#define M_ 4096
#define D_ 128

typedef __attribute__((ext_vector_type(8))) short s8;     // 8 bf16 (4 VGPRs)
typedef __attribute__((ext_vector_type(4))) float f4;     // MFMA C/D + float4 loads
typedef __attribute__((ext_vector_type(16))) float f16v;  // 32x32 MFMA C/D
typedef __attribute__((ext_vector_type(4))) unsigned short us4;
typedef unsigned short u16;

__device__ __forceinline__ u16 f2b(float f) {   // RNE float->bf16
  unsigned int x = __float_as_uint(f);
  unsigned int r = x + 0x7fffu + ((x >> 16) & 1u);
  return (u16)(r >> 16);
}
__device__ __forceinline__ s8 ld8(const u16* p) {
  return *reinterpret_cast<const s8*>(p);
}
__device__ __forceinline__ s8 ldcvt8(const float* p) {
  f4 x = *reinterpret_cast<const f4*>(p);
  f4 y = *reinterpret_cast<const f4*>(p + 4);
  s8 r;
  r[0] = (short)f2b(x[0]); r[1] = (short)f2b(x[1]);
  r[2] = (short)f2b(x[2]); r[3] = (short)f2b(x[3]);
  r[4] = (short)f2b(y[0]); r[5] = (short)f2b(y[1]);
  r[6] = (short)f2b(y[2]); r[7] = (short)f2b(y[3]);
  return r;
}
__device__ __forceinline__ f4 mfma16(s8 a, s8 b, f4 c) {
  return __builtin_amdgcn_mfma_f32_16x16x32_bf16(a, b, c, 0, 0, 0);
}
__device__ __forceinline__ f16v mfma32(s8 a, s8 b, f16v c) {
  return __builtin_amdgcn_mfma_f32_32x32x16_bf16(a, b, c, 0, 0, 0);
}
// XOR-swizzled LDS offset for 256B rows. off = byte offset in row.
__device__ __forceinline__ int swz(int row, int off) {
  return (row << 8) + ((((off >> 4) ^ (row & 15)) << 4) | (off & 15));
}
// scale * log2(e): exp(s/sqrt(128)) == exp2(s * CS)
#define CS 0.1275174365f

// Transpose seven 128x128 f32 weight matrices into ws as bf16 Wt[n][k] (B-frags).
__global__ void wtrans(const float* a0, const float* a1, const float* a2, const float* a3,
                       const float* a4, const float* a5, const float* a6, u16* dst) {
  const float* s;
  switch (blockIdx.x) {
    case 0: s = a0; break; case 1: s = a1; break; case 2: s = a2; break;
    case 3: s = a3; break; case 4: s = a4; break; case 5: s = a5; break;
    default: s = a6; break;
  }
  u16* d = dst + blockIdx.x * 16384;
  for (int i = threadIdx.x; i < 16384; i += 256) {
    int r = i >> 7, c = i & 127;
    d[c * 128 + r] = f2b(s[i]);
  }
}

// Fused 2-layer MLP: out = relu(X@W1+b1)@W2+b2 (X f32, out bf16 in ws).
__global__ __launch_bounds__(256) void mlp2q(const float* __restrict__ X,
    const u16* __restrict__ W1t, const float* __restrict__ b1,
    const u16* __restrict__ W2t, const float* __restrict__ b2,
    u16* __restrict__ out) {
  __shared__ u16 H[64][136];
  const int tid = threadIdx.x;
  const int wave = tid >> 6, lane = tid & 63;
  const int c16 = lane & 15, quad = lane >> 4;
  const long row0 = (long)blockIdx.x * 64 + wave * 16;

  s8 a[4];
  {
    const float* xr = X + (row0 + c16) * D_ + quad * 8;
    #pragma unroll
    for (int kk = 0; kk < 4; kk++) a[kk] = ldcvt8(xr + kk * 32);
  }
  #pragma unroll
  for (int ns = 0; ns < 8; ns++) {
    f4 acc = {0.f, 0.f, 0.f, 0.f};
    const int c = ns * 16 + c16;
    const u16* wr = W1t + (long)c * 128 + quad * 8;
    #pragma unroll
    for (int kk = 0; kk < 4; kk++) acc = mfma16(a[kk], ld8(wr + kk * 32), acc);
    const float bias = b1[c];
    #pragma unroll
    for (int r = 0; r < 4; r++) {
      float v = acc[r] + bias;
      H[wave * 16 + quad * 4 + r][c] = f2b(v > 0.f ? v : 0.f);
    }
  }
  __syncthreads();
  s8 a2[4];
  #pragma unroll
  for (int kk = 0; kk < 4; kk++)
    a2[kk] = *reinterpret_cast<const s8*>(&H[wave * 16 + c16][kk * 32 + quad * 8]);
  #pragma unroll
  for (int ns = 0; ns < 8; ns++) {
    f4 acc = {0.f, 0.f, 0.f, 0.f};
    const int c = ns * 16 + c16;
    const u16* wr = W2t + (long)c * 128 + quad * 8;
    #pragma unroll
    for (int kk = 0; kk < 4; kk++) acc = mfma16(a2[kk], ld8(wr + kk * 32), acc);
    const float bias = b2[c];
    #pragma unroll
    for (int r = 0; r < 4; r++)
      out[(row0 + quad * 4 + r) * D_ + c] = f2b(acc[r] + bias);
  }
}

// Fused: kpv = beta-MLP(p_feat) + delta-MLP(|p_xyz - v_xyz|)  AND
//        vt  = omega-MLP(p_feat) stored transposed [b][d][n].
// Shares the X A-frags across all three MLPs; H reused sequentially.
__global__ __launch_bounds__(256) void kpv_omega(
    const float* __restrict__ pf, const float* __restrict__ pxyz, const float* __restrict__ vxyz,
    const u16* __restrict__ bW1t, const float* __restrict__ bb1,
    const u16* __restrict__ bW2t, const float* __restrict__ bb2,
    const float* __restrict__ dW1, const float* __restrict__ db1,
    const u16* __restrict__ dW2t, const float* __restrict__ db2,
    const u16* __restrict__ oW1t, const float* __restrict__ ob1,
    const u16* __restrict__ oW2t, const float* __restrict__ ob2,
    u16* __restrict__ kpv_out, u16* __restrict__ vt_out) {
  __shared__ u16 H[64][136];
  const int tid = threadIdx.x;
  const int wave = tid >> 6, lane = tid & 63;
  const int c16 = lane & 15, quad = lane >> 4;
  const long row0 = (long)blockIdx.x * 64 + wave * 16;

  s8 a[4];
  {
    const float* xr = pf + (row0 + c16) * D_ + quad * 8;
    #pragma unroll
    for (int kk = 0; kk < 4; kk++) a[kk] = ldcvt8(xr + kk * 32);
  }
  // ---- beta layer 1 -> H ----
  #pragma unroll
  for (int ns = 0; ns < 8; ns++) {
    f4 acc = {0.f, 0.f, 0.f, 0.f};
    const int c = ns * 16 + c16;
    const u16* wr = bW1t + (long)c * 128 + quad * 8;
    #pragma unroll
    for (int kk = 0; kk < 4; kk++) acc = mfma16(a[kk], ld8(wr + kk * 32), acc);
    const float bias = bb1[c];
    #pragma unroll
    for (int r = 0; r < 4; r++) {
      float v = acc[r] + bias;
      H[wave * 16 + quad * 4 + r][c] = f2b(v > 0.f ? v : 0.f);
    }
  }
  __syncthreads();
  f4 acc2[8];
  #pragma unroll
  for (int ns = 0; ns < 8; ns++) acc2[ns] = (f4){0.f, 0.f, 0.f, 0.f};
  {
    s8 a2[4];
    #pragma unroll
    for (int kk = 0; kk < 4; kk++)
      a2[kk] = *reinterpret_cast<const s8*>(&H[wave * 16 + c16][kk * 32 + quad * 8]);
    #pragma unroll
    for (int ns = 0; ns < 8; ns++) {
      const u16* wr = bW2t + (long)(ns * 16 + c16) * 128 + quad * 8;
      #pragma unroll
      for (int kk = 0; kk < 4; kk++) acc2[ns] = mfma16(a2[kk], ld8(wr + kk * 32), acc2[ns]);
    }
  }
  __syncthreads();                               // beta reads done -> delta writes
  // ---- delta hidden (Din=3, VALU) -> H ----
  {
    const long bat = ((long)blockIdx.x * 64) / N_;
    const float vx0 = vxyz[bat * 3 + 0];
    const float vx1 = vxyz[bat * 3 + 1];
    const float vx2 = vxyz[bat * 3 + 2];
    for (int i = 0; i < 32; i++) {
      const int e = lane + 64 * i;
      const int rr = e >> 7, cc = e & 127;
      const long gr = row0 + rr;
      const float d0 = fabsf(pxyz[gr * 3 + 0] - vx0);
      const float d1 = fabsf(pxyz[gr * 3 + 1] - vx1);
      const float d2 = fabsf(pxyz[gr * 3 + 2] - vx2);
      float h = d0 * dW1[cc] + d1 * dW1[128 + cc] + d2 * dW1[256 + cc] + db1[cc];
      H[wave * 16 + rr][cc] = f2b(h > 0.f ? h : 0.f);
    }
  }
  __syncthreads();                               // delta write -> delta read
  {
    s8 a2[4];
    #pragma unroll
    for (int kk = 0; kk < 4; kk++)
      a2[kk] = *reinterpret_cast<const s8*>(&H[wave * 16 + c16][kk * 32 + quad * 8]);
    #pragma unroll
    for (int ns = 0; ns < 8; ns++) {
      const u16* wr = dW2t + (long)(ns * 16 + c16) * 128 + quad * 8;
      #pragma unroll
      for (int kk = 0; kk < 4; kk++) acc2[ns] = mfma16(a2[kk], ld8(wr + kk * 32), acc2[ns]);
    }
  }
  #pragma unroll
  for (int ns = 0; ns < 8; ns++) {
    const int c = ns * 16 + c16;
    const float bias = bb2[c] + db2[c];
    #pragma unroll
    for (int r = 0; r < 4; r++)
      kpv_out[(row0 + quad * 4 + r) * D_ + c] = f2b(acc2[ns][r] + bias);
  }
  __syncthreads();                               // delta reads done -> omega writes
  // ---- omega layer 1 -> H ----
  #pragma unroll
  for (int ns = 0; ns < 8; ns++) {
    f4 acc = {0.f, 0.f, 0.f, 0.f};
    const int c = ns * 16 + c16;
    const u16* wr = oW1t + (long)c * 128 + quad * 8;
    #pragma unroll
    for (int kk = 0; kk < 4; kk++) acc = mfma16(a[kk], ld8(wr + kk * 32), acc);
    const float bias = ob1[c];
    #pragma unroll
    for (int r = 0; r < 4; r++) {
      float v = acc[r] + bias;
      H[wave * 16 + quad * 4 + r][c] = f2b(v > 0.f ? v : 0.f);
    }
  }
  __syncthreads();
  {
    s8 a2[4];
    #pragma unroll
    for (int kk = 0; kk < 4; kk++)
      a2[kk] = *reinterpret_cast<const s8*>(&H[wave * 16 + c16][kk * 32 + quad * 8]);
    #pragma unroll
    for (int ns = 0; ns < 8; ns++) {
      f4 acc = {0.f, 0.f, 0.f, 0.f};
      const int c = ns * 16 + c16;
      const u16* wr = oW2t + (long)c * 128 + quad * 8;
      #pragma unroll
      for (int kk = 0; kk < 4; kk++) acc = mfma16(a2[kk], ld8(wr + kk * 32), acc);
      const float bias = ob2[c];
      const long g = row0 + quad * 4;
      const long bb = g >> 14;
      const long n = g & (N_ - 1);
      us4 pk;
      #pragma unroll
      for (int r = 0; r < 4; r++) pk[r] = f2b(acc[r] + bias);
      *reinterpret_cast<us4*>(vt_out + bb * (long)128 * N_ + (long)c * N_ + n) = pk;
    }
  }
}

// Pass 1 v3: 512 thr, 8 waves x 32 n = 256 n/block, m-split x4 (1024 m each).
// mfma32, split-K chains, per-lane sum16 accumulators; partial sums -> sums[].
__global__ __launch_bounds__(512, 4) void colsum_v3(const u16* __restrict__ q,
    const u16* __restrict__ kpv, float* __restrict__ sums) {
  __shared__ char LQ[16384];                     // 64 m x 128 k bf16, swizzled
  const int tid = threadIdx.x;
  const int wave = tid >> 6, lane = tid & 63;
  const int l31 = lane & 31, hi = lane >> 5;
  const int bid = blockIdx.x;                    // b(2) x nbpart(64) x mq(4)
  const int mq = bid & 3;
  const int nbpart = (bid >> 2) & 63;
  const int b = bid >> 8;
  const int nb = nbpart * 256 + wave * 32;
  const int rsub = lane >> 4, ch = lane & 15;

  s8 ak[8];                                      // KPV A-frag: 32 n rows, K=128
  {
    const u16* kr = kpv + ((long)b * N_ + nb + l31) * D_ + hi * 8;
    #pragma unroll
    for (int kk = 0; kk < 8; kk++) ak[kk] = ld8(kr + kk * 16);
  }
  float sum16[16];
  #pragma unroll
  for (int r = 0; r < 16; r++) sum16[r] = 0.f;
  const u16* qb = q + (long)b * M_ * D_ + (long)mq * 1024 * D_;

  for (int m0 = 0; m0 < 1024; m0 += 64) {
    // stage Q rows m0..m0+63 (8 waves x 8 rows)
    s8 t0 = ld8(qb + (long)(m0 + wave * 8 + rsub) * D_ + ch * 8);
    s8 t1 = ld8(qb + (long)(m0 + wave * 8 + 4 + rsub) * D_ + ch * 8);
    *reinterpret_cast<s8*>(LQ + swz(wave * 8 + rsub, ch * 16)) = t0;
    *reinterpret_cast<s8*>(LQ + swz(wave * 8 + 4 + rsub, ch * 16)) = t1;
    __syncthreads();
    #pragma unroll
    for (int mt = 0; mt < 2; mt++) {
      f16v st0, st1;
      #pragma unroll
      for (int r = 0; r < 16; r++) { st0[r] = 0.f; st1[r] = 0.f; }
      #pragma unroll
      for (int kk = 0; kk < 4; kk++) {
        s8 bq0 = *reinterpret_cast<const s8*>(LQ + swz(mt * 32 + l31, kk * 32 + hi * 16));
        s8 bq1 = *reinterpret_cast<const s8*>(LQ + swz(mt * 32 + l31, (kk + 4) * 32 + hi * 16));
        st0 = mfma32(ak[kk], bq0, st0);
        st1 = mfma32(ak[kk + 4], bq1, st1);
      }
      #pragma unroll
      for (int r = 0; r < 16; r++) sum16[r] += exp2f((st0[r] + st1[r]) * CS);
    }
    __syncthreads();                             // WAR: Q reads vs next stage
  }
  // reduce over the 32 m-lanes (l31); hi stays fixed (masks <= 16)
  #pragma unroll
  for (int mask = 1; mask < 32; mask <<= 1) {
    if (mask == 32) break;
    #pragma unroll
    for (int r = 0; r < 16; r++) sum16[r] += __shfl_xor(sum16[r], mask, 64);
  }
  if (l31 == 0) {
    float* sp = sums + (long)mq * (B_ * N_) + (long)b * N_ + nb;
    #pragma unroll
    for (int g = 0; g < 4; g++)
      #pragma unroll
      for (int r = 0; r < 4; r++)
        sp[8 * g + 4 * hi + r] = sum16[g * 4 + r];
  }
}

// inv = 1 / (sum of 4 m-split partials)
__global__ __launch_bounds__(256) void recip_k(const float* __restrict__ sums,
                                               float* __restrict__ inv) {
  const int i = blockIdx.x * 256 + threadIdx.x;  // 0 .. B*N-1
  const float s = sums[i] + sums[B_ * N_ + i] + sums[2 * B_ * N_ + i]
                + sums[3 * B_ * N_ + i];
  inv[i] = 1.f / s;
}

// Pass 2a v8: as v7 (verified) + split-K S chains + Vt loads hoisted to the
// top of the iteration (consumed 2 barriers later -> L2 latency hidden).
__global__ __launch_bounds__(256, 4) void attn_v8(const u16* __restrict__ q,
    const u16* __restrict__ kpv, const u16* __restrict__ vt,
    const float* __restrict__ inv, float* __restrict__ part,
    int lgns, int nslice) {
  __shared__ char LK[16384];
  __shared__ char LP[8192];
  const int tid = threadIdx.x;
  const int wave = tid >> 6, lane = tid & 63;
  const int l31 = lane & 31, hi = lane >> 5;
  const int bid = blockIdx.x;                    // b x mb(64) x ns
  const int ns = bid & ((1 << lgns) - 1);
  const int mb = (bid >> lgns) & 63;
  const int b = bid >> (lgns + 6);
  const int nt = wave & 1, mt = wave >> 1;       // S^T tile: 32n x 32m
  const int m_base = mb * 64;
  const int n_begin = ns * nslice;
  const int rsub = lane >> 4, ch = lane & 15;    // staging roles

  const u16* kpb = kpv + (long)b * N_ * D_;
  const u16* vtb = vt + (long)b * (long)D_ * N_;
  const float* invb = inv + (long)b * N_;

  s8 bq[8];                                      // Q B-frags: 8 ksteps (K=128)
  {
    const u16* qr = q + ((long)b * M_ + m_base + mt * 32 + l31) * D_ + hi * 8;
    #pragma unroll
    for (int kk = 0; kk < 8; kk++) bq[kk] = ld8(qr + kk * 16);
  }
  f16v acc[2];                                   // O: 2 m-tiles x wave's 32 d
  #pragma unroll
  for (int i = 0; i < 2; i++)
    #pragma unroll
    for (int r = 0; r < 16; r++) acc[i][r] = 0.f;

  // preload first KPV chunk into regs
  s8 tmp[4];
  #pragma unroll
  for (int i = 0; i < 4; i++)
    tmp[i] = ld8(kpb + (long)(n_begin + wave * 16 + i * 4 + rsub) * D_ + ch * 8);

  for (int n0 = n_begin; n0 < n_begin + nslice; n0 += 64) {
    // write staged KPV(i) -> LK
    #pragma unroll
    for (int i = 0; i < 4; i++)
      *reinterpret_cast<s8*>(LK + swz(wave * 16 + i * 4 + rsub, ch * 16)) = tmp[i];
    // Vt for THIS iter's PV (consumed after 2 barriers -> latency hidden)
    s8 bv[4];
    #pragma unroll
    for (int kk = 0; kk < 4; kk++)
      bv[kk] = ld8(vtb + (long)(wave * 32 + l31) * N_ + n0 + kk * 16 + hi * 8);
    // prefetch KPV(i+1)
    {
      int nn = n0 + 64;
      if (nn >= n_begin + nslice) nn = n_begin;  // last iter: dummy (unused)
      #pragma unroll
      for (int i = 0; i < 4; i++)
        tmp[i] = ld8(kpb + (long)(nn + wave * 16 + i * 4 + rsub) * D_ + ch * 8);
    }
    __syncthreads();                             // LK ready; LP safe (PV(i-1) done)
    // ---- S^T: wave tile 32n(nt) x 32m(mt), K=128, two chains ----
    {
      f16v st0, st1;
      #pragma unroll
      for (int r = 0; r < 16; r++) { st0[r] = 0.f; st1[r] = 0.f; }
      #pragma unroll
      for (int kk = 0; kk < 4; kk++) {
        s8 aK0 = *reinterpret_cast<const s8*>(LK + swz(nt * 32 + l31, kk * 32 + hi * 16));
        s8 aK1 = *reinterpret_cast<const s8*>(LK + swz(nt * 32 + l31, (kk + 4) * 32 + hi * 16));
        st0 = mfma32(aK0, bq[kk], st0);
        st1 = mfma32(aK1, bq[kk + 4], st1);
      }
      // C: col=m (l31), row n = nt*32 + 8g + 4hi + r  (reg = g*4+r)
      #pragma unroll
      for (int g = 0; g < 4; g++) {
        const f4 ic = *reinterpret_cast<const f4*>(invb + n0 + nt * 32 + 8 * g + 4 * hi);
        us4 pk;
        #pragma unroll
        for (int r = 0; r < 4; r++)
          pk[r] = (u16)(__float_as_uint(exp2f((st0[g * 4 + r] + st1[g * 4 + r]) * CS) * ic[r]) >> 16);
        *reinterpret_cast<us4*>(LP + (4 * nt + g) * 1024 + (mt * 32 + l31) * 16 + 8 * hi) = pk;
      }
    }
    __syncthreads();                             // LP ready; LK(i) reads done
    // ---- PV: wave owns 32 d, both m-tiles, K=64 (2 chains) ----
    #pragma unroll
    for (int kk = 0; kk < 4; kk++) {
      #pragma unroll
      for (int i = 0; i < 2; i++) {
        s8 ap = *reinterpret_cast<const s8*>(
            LP + (2 * kk + hi) * 1024 + (i * 32 + l31) * 16);
        acc[i] = mfma32(ap, bv[kk], acc[i]);
      }
    }
  }
  // store partial tile [64m][128d] f32; C: col=d, row m=(reg&3)+8*(reg>>2)+4*hi
  float* pt = part + (long)bid * 64 * 128;
  #pragma unroll
  for (int i = 0; i < 2; i++)
    #pragma unroll
    for (int g = 0; g < 4; g++)
      #pragma unroll
      for (int r = 0; r < 4; r++)
        pt[(i * 32 + g * 8 + 4 * hi + r) * 128 + wave * 32 + l31] = acc[i][g * 4 + r];
}

// Pass 2b: out = sum_ns partial + vfeat  (f32 out)
__global__ __launch_bounds__(256) void attn_reduce(const float* __restrict__ part,
    const float* __restrict__ vfeat, float* __restrict__ out, int nsplit) {
  const int g4 = blockIdx.x * 256 + threadIdx.x;     // 0 .. B*M*D/4-1
  const int b = g4 >> 17;                            // M*D/4 = 131072
  const int rem = g4 & 131071;
  const int m = rem >> 5;
  const int d4 = rem & 31;
  const int mb = m >> 6, mr = m & 63;
  const long base = ((long)(b * 64 + mb) * nsplit) * 8192 + mr * 128 + d4 * 4;
  f4 s = *reinterpret_cast<const f4*>(vfeat + (long)g4 * 4);
  for (int ns = 0; ns < nsplit; ns++)
    s += *reinterpret_cast<const f4*>(part + base + ns * 8192);
  *reinterpret_cast<f4*>(out + (long)g4 * 4) = s;
}

extern "C" void kernel_launch(void* const* d_in, const int* in_sizes, int n_in,
                              void* d_out, int out_size, void* d_ws, size_t ws_size,
                              hipStream_t stream) {
  const float* p_xyz  = (const float*)d_in[0];
  const float* v_xyz  = (const float*)d_in[1];
  const float* p_feat = (const float*)d_in[2];
  const float* v_feat = (const float*)d_in[3];
  const float* aW1 = (const float*)d_in[4],  *ab1 = (const float*)d_in[5];
  const float* aW2 = (const float*)d_in[6],  *ab2 = (const float*)d_in[7];
  const float* bW1 = (const float*)d_in[8],  *bb1 = (const float*)d_in[9];
  const float* bW2 = (const float*)d_in[10], *bb2 = (const float*)d_in[11];
  const float* oW1 = (const float*)d_in[12], *ob1 = (const float*)d_in[13];
  const float* oW2 = (const float*)d_in[14], *ob2 = (const float*)d_in[15];
  const float* dW1 = (const float*)d_in[16], *db1 = (const float*)d_in[17];
  const float* dW2 = (const float*)d_in[18], *db2 = (const float*)d_in[19];

  char* ws = (char*)d_ws;
  u16* wt    = (u16*)ws;                               // 7 * 16384 bf16 elems
  u16* aW1t  = wt + 0 * 16384;
  u16* aW2t  = wt + 1 * 16384;
  u16* bW1t  = wt + 2 * 16384;
  u16* bW2t  = wt + 3 * 16384;
  u16* oW1t  = wt + 4 * 16384;
  u16* oW2t  = wt + 5 * 16384;
  u16* dW2t  = wt + 6 * 16384;
  u16* qbuf  = (u16*)(ws + 262144);                    // B*M*D bf16 = 2 MB
  u16* kpvb  = (u16*)(ws + 2359296);                   // B*N*D bf16 = 8 MB
  u16* vtb   = (u16*)(ws + 10747904);                  // Vt = 8 MB
  float* invb = (float*)(ws + 19136512);               // B*N f32 = 128 KB
  float* partb = (float*)(ws + 19267584);              // nsplit * 4 MB
  float* sums  = partb;                                // 512 KB, consumed pre-attn

  const size_t part_off = 19267584;
  int lgns = (ws_size >= part_off + (size_t)8 * B_ * M_ * D_ * 4) ? 3 : 2;
  const int nsplit = 1 << lgns;
  const int nslice = N_ / nsplit;

  wtrans<<<dim3(7), dim3(256), 0, stream>>>(aW1, aW2, bW1, bW2, oW1, oW2, dW2, wt);
  mlp2q<<<dim3((B_ * M_) / 64), dim3(256), 0, stream>>>(v_feat, aW1t, ab1, aW2t, ab2, qbuf);
  kpv_omega<<<dim3((B_ * N_) / 64), dim3(256), 0, stream>>>(
      p_feat, p_xyz, v_xyz, bW1t, bb1, bW2t, bb2, dW1, db1, dW2t, db2,
      oW1t, ob1, oW2t, ob2, kpvb, vtb);
  colsum_v3<<<dim3(B_ * 64 * 4), dim3(512), 0, stream>>>(qbuf, kpvb, sums);
  recip_k<<<dim3((B_ * N_) / 256), dim3(256), 0, stream>>>(sums, invb);
  attn_v8<<<dim3(B_ * 64 * nsplit), dim3(256), 0, stream>>>(qbuf, kpvb, vtb, invb, partb,
                                                            lgns, nslice);
  attn_reduce<<<dim3((B_ * M_ * D_ / 4) / 256), dim3(256), 0, stream>>>(partb, v_feat,
                                                                        (float*)d_out,
                                                                        nsplit);
}

// Round 10
// 388.544 us; speedup vs baseline: 1.2037x; 1.2037x over previous
//
#include <hip/hip_runtime.h>

#define B_ 2
#define N_ 16384
#define M_ 4096
#define D_ 128

typedef __attribute__((ext_vector_type(8))) short s8;     // 8 bf16 (4 VGPRs)
typedef __attribute__((ext_vector_type(4))) float f4;     // MFMA C/D + float4 loads
typedef __attribute__((ext_vector_type(16))) float f16v;  // 32x32 MFMA C/D
typedef __attribute__((ext_vector_type(4))) unsigned short us4;
typedef unsigned short u16;

__device__ __forceinline__ u16 f2b(float f) {   // RNE float->bf16
  unsigned int x = __float_as_uint(f);
  unsigned int r = x + 0x7fffu + ((x >> 16) & 1u);
  return (u16)(r >> 16);
}
__device__ __forceinline__ s8 ld8(const u16* p) {
  return *reinterpret_cast<const s8*>(p);
}
__device__ __forceinline__ s8 ldcvt8(const float* p) {
  f4 x = *reinterpret_cast<const f4*>(p);
  f4 y = *reinterpret_cast<const f4*>(p + 4);
  s8 r;
  r[0] = (short)f2b(x[0]); r[1] = (short)f2b(x[1]);
  r[2] = (short)f2b(x[2]); r[3] = (short)f2b(x[3]);
  r[4] = (short)f2b(y[0]); r[5] = (short)f2b(y[1]);
  r[6] = (short)f2b(y[2]); r[7] = (short)f2b(y[3]);
  return r;
}
__device__ __forceinline__ f4 mfma16(s8 a, s8 b, f4 c) {
  return __builtin_amdgcn_mfma_f32_16x16x32_bf16(a, b, c, 0, 0, 0);
}
__device__ __forceinline__ f16v mfma32(s8 a, s8 b, f16v c) {
  return __builtin_amdgcn_mfma_f32_32x32x16_bf16(a, b, c, 0, 0, 0);
}
// XOR-swizzled LDS offset for 256B rows. off = byte offset in row.
__device__ __forceinline__ int swz(int row, int off) {
  return (row << 8) + ((((off >> 4) ^ (row & 15)) << 4) | (off & 15));
}
// scale * log2(e): exp(s/sqrt(128)) == exp2(s * CS)
#define CS 0.1275174365f

// Transpose seven 128x128 f32 weight matrices into ws as bf16 Wt[n][k] (B-frags).
__global__ void wtrans(const float* a0, const float* a1, const float* a2, const float* a3,
                       const float* a4, const float* a5, const float* a6, u16* dst) {
  const float* s;
  switch (blockIdx.x) {
    case 0: s = a0; break; case 1: s = a1; break; case 2: s = a2; break;
    case 3: s = a3; break; case 4: s = a4; break; case 5: s = a5; break;
    default: s = a6; break;
  }
  u16* d = dst + blockIdx.x * 16384;
  for (int i = threadIdx.x; i < 16384; i += 256) {
    int r = i >> 7, c = i & 127;
    d[c * 128 + r] = f2b(s[i]);
  }
}

// Fused 2-layer MLP for Q: out = relu(X@W1+b1)@W2+b2 (X f32, out bf16 in ws).
__global__ __launch_bounds__(256) void mlp2q(const float* __restrict__ X,
    const u16* __restrict__ W1t, const float* __restrict__ b1,
    const u16* __restrict__ W2t, const float* __restrict__ b2,
    u16* __restrict__ out) {
  __shared__ u16 H[64][136];
  const int tid = threadIdx.x;
  const int wave = tid >> 6, lane = tid & 63;
  const int c16 = lane & 15, quad = lane >> 4;
  const long row0 = (long)blockIdx.x * 64 + wave * 16;

  s8 a[4];
  {
    const float* xr = X + (row0 + c16) * D_ + quad * 8;
    #pragma unroll
    for (int kk = 0; kk < 4; kk++) a[kk] = ldcvt8(xr + kk * 32);
  }
  #pragma unroll
  for (int ns = 0; ns < 8; ns++) {
    f4 acc = {0.f, 0.f, 0.f, 0.f};
    const int c = ns * 16 + c16;
    const u16* wr = W1t + (long)c * 128 + quad * 8;
    #pragma unroll
    for (int kk = 0; kk < 4; kk++) acc = mfma16(a[kk], ld8(wr + kk * 32), acc);
    const float bias = b1[c];
    #pragma unroll
    for (int r = 0; r < 4; r++) {
      float v = acc[r] + bias;
      H[wave * 16 + quad * 4 + r][c] = f2b(v > 0.f ? v : 0.f);
    }
  }
  __syncthreads();
  s8 a2[4];
  #pragma unroll
  for (int kk = 0; kk < 4; kk++)
    a2[kk] = *reinterpret_cast<const s8*>(&H[wave * 16 + c16][kk * 32 + quad * 8]);
  #pragma unroll
  for (int ns = 0; ns < 8; ns++) {
    f4 acc = {0.f, 0.f, 0.f, 0.f};
    const int c = ns * 16 + c16;
    const u16* wr = W2t + (long)c * 128 + quad * 8;
    #pragma unroll
    for (int kk = 0; kk < 4; kk++) acc = mfma16(a2[kk], ld8(wr + kk * 32), acc);
    const float bias = b2[c];
    #pragma unroll
    for (int r = 0; r < 4; r++)
      out[(row0 + quad * 4 + r) * D_ + c] = f2b(acc[r] + bias);
  }
}

// Fused: kpv = beta-MLP(p_feat) + delta-MLP(|p_xyz - v_xyz|)  AND
//        vt  = omega-MLP(p_feat) stored transposed [b][d][n].
// Shares the X A-frags across all three MLPs; H reused sequentially.
__global__ __launch_bounds__(256) void kpv_omega(
    const float* __restrict__ pf, const float* __restrict__ pxyz, const float* __restrict__ vxyz,
    const u16* __restrict__ bW1t, const float* __restrict__ bb1,
    const u16* __restrict__ bW2t, const float* __restrict__ bb2,
    const float* __restrict__ dW1, const float* __restrict__ db1,
    const u16* __restrict__ dW2t, const float* __restrict__ db2,
    const u16* __restrict__ oW1t, const float* __restrict__ ob1,
    const u16* __restrict__ oW2t, const float* __restrict__ ob2,
    u16* __restrict__ kpv_out, u16* __restrict__ vt_out) {
  __shared__ u16 H[64][136];
  const int tid = threadIdx.x;
  const int wave = tid >> 6, lane = tid & 63;
  const int c16 = lane & 15, quad = lane >> 4;
  const long row0 = (long)blockIdx.x * 64 + wave * 16;

  s8 a[4];
  {
    const float* xr = pf + (row0 + c16) * D_ + quad * 8;
    #pragma unroll
    for (int kk = 0; kk < 4; kk++) a[kk] = ldcvt8(xr + kk * 32);
  }
  // ---- beta layer 1 -> H ----
  #pragma unroll
  for (int ns = 0; ns < 8; ns++) {
    f4 acc = {0.f, 0.f, 0.f, 0.f};
    const int c = ns * 16 + c16;
    const u16* wr = bW1t + (long)c * 128 + quad * 8;
    #pragma unroll
    for (int kk = 0; kk < 4; kk++) acc = mfma16(a[kk], ld8(wr + kk * 32), acc);
    const float bias = bb1[c];
    #pragma unroll
    for (int r = 0; r < 4; r++) {
      float v = acc[r] + bias;
      H[wave * 16 + quad * 4 + r][c] = f2b(v > 0.f ? v : 0.f);
    }
  }
  __syncthreads();
  f4 acc2[8];
  #pragma unroll
  for (int ns = 0; ns < 8; ns++) acc2[ns] = (f4){0.f, 0.f, 0.f, 0.f};
  {
    s8 a2[4];
    #pragma unroll
    for (int kk = 0; kk < 4; kk++)
      a2[kk] = *reinterpret_cast<const s8*>(&H[wave * 16 + c16][kk * 32 + quad * 8]);
    #pragma unroll
    for (int ns = 0; ns < 8; ns++) {
      const u16* wr = bW2t + (long)(ns * 16 + c16) * 128 + quad * 8;
      #pragma unroll
      for (int kk = 0; kk < 4; kk++) acc2[ns] = mfma16(a2[kk], ld8(wr + kk * 32), acc2[ns]);
    }
  }
  __syncthreads();                               // beta reads done -> delta writes
  // ---- delta hidden (Din=3, VALU) -> H ----
  {
    const long bat = ((long)blockIdx.x * 64) / N_;
    const float vx0 = vxyz[bat * 3 + 0];
    const float vx1 = vxyz[bat * 3 + 1];
    const float vx2 = vxyz[bat * 3 + 2];
    for (int i = 0; i < 32; i++) {
      const int e = lane + 64 * i;
      const int rr = e >> 7, cc = e & 127;
      const long gr = row0 + rr;
      const float d0 = fabsf(pxyz[gr * 3 + 0] - vx0);
      const float d1 = fabsf(pxyz[gr * 3 + 1] - vx1);
      const float d2 = fabsf(pxyz[gr * 3 + 2] - vx2);
      float h = d0 * dW1[cc] + d1 * dW1[128 + cc] + d2 * dW1[256 + cc] + db1[cc];
      H[wave * 16 + rr][cc] = f2b(h > 0.f ? h : 0.f);
    }
  }
  __syncthreads();                               // delta write -> delta read
  {
    s8 a2[4];
    #pragma unroll
    for (int kk = 0; kk < 4; kk++)
      a2[kk] = *reinterpret_cast<const s8*>(&H[wave * 16 + c16][kk * 32 + quad * 8]);
    #pragma unroll
    for (int ns = 0; ns < 8; ns++) {
      const u16* wr = dW2t + (long)(ns * 16 + c16) * 128 + quad * 8;
      #pragma unroll
      for (int kk = 0; kk < 4; kk++) acc2[ns] = mfma16(a2[kk], ld8(wr + kk * 32), acc2[ns]);
    }
  }
  #pragma unroll
  for (int ns = 0; ns < 8; ns++) {
    const int c = ns * 16 + c16;
    const float bias = bb2[c] + db2[c];
    #pragma unroll
    for (int r = 0; r < 4; r++)
      kpv_out[(row0 + quad * 4 + r) * D_ + c] = f2b(acc2[ns][r] + bias);
  }
  __syncthreads();                               // delta reads done -> omega writes
  // ---- omega layer 1 -> H ----
  #pragma unroll
  for (int ns = 0; ns < 8; ns++) {
    f4 acc = {0.f, 0.f, 0.f, 0.f};
    const int c = ns * 16 + c16;
    const u16* wr = oW1t + (long)c * 128 + quad * 8;
    #pragma unroll
    for (int kk = 0; kk < 4; kk++) acc = mfma16(a[kk], ld8(wr + kk * 32), acc);
    const float bias = ob1[c];
    #pragma unroll
    for (int r = 0; r < 4; r++) {
      float v = acc[r] + bias;
      H[wave * 16 + quad * 4 + r][c] = f2b(v > 0.f ? v : 0.f);
    }
  }
  __syncthreads();
  {
    s8 a2[4];
    #pragma unroll
    for (int kk = 0; kk < 4; kk++)
      a2[kk] = *reinterpret_cast<const s8*>(&H[wave * 16 + c16][kk * 32 + quad * 8]);
    #pragma unroll
    for (int ns = 0; ns < 8; ns++) {
      f4 acc = {0.f, 0.f, 0.f, 0.f};
      const int c = ns * 16 + c16;
      const u16* wr = oW2t + (long)c * 128 + quad * 8;
      #pragma unroll
      for (int kk = 0; kk < 4; kk++) acc = mfma16(a2[kk], ld8(wr + kk * 32), acc);
      const float bias = ob2[c];
      const long g = row0 + quad * 4;
      const long bb = g >> 14;
      const long n = g & (N_ - 1);
      us4 pk;
      #pragma unroll
      for (int r = 0; r < 4; r++) pk[r] = f2b(acc[r] + bias);
      *reinterpret_cast<us4*>(vt_out + bb * (long)128 * N_ + (long)c * N_ + n) = pk;
    }
  }
}

// Pass 1 v2 (round-8 verified): block owns 128 n; stage Q chunks in LDS,
// S^T via mfma16(kpv,q), exp2 accumulate, cross-lane reduce, write inv.
__global__ __launch_bounds__(512, 6) void colsum_v2(const u16* __restrict__ q,
    const u16* __restrict__ kpv, float* __restrict__ inv) {
  __shared__ char LQ[16384];                     // 64 m x 128 k bf16, swizzled
  const int tid = threadIdx.x;
  const int wave = tid >> 6, lane = tid & 63;
  const int c16 = lane & 15, quad = lane >> 4;
  const int b = blockIdx.x >> 7;
  const int nb = (blockIdx.x & 127) * 128 + wave * 16;
  const int rsub = lane >> 4, ch = lane & 15;

  s8 ak[4];
  {
    const u16* kr = kpv + ((long)b * N_ + nb + c16) * D_ + quad * 8;
    #pragma unroll
    for (int kk = 0; kk < 4; kk++) ak[kk] = ld8(kr + kk * 32);
  }
  f4 sum = {0.f, 0.f, 0.f, 0.f};
  const u16* qb = q + (long)b * M_ * D_;

  for (int m0 = 0; m0 < M_; m0 += 64) {
    s8 t0 = ld8(qb + (long)(m0 + wave * 8 + rsub) * D_ + ch * 8);
    s8 t1 = ld8(qb + (long)(m0 + wave * 8 + 4 + rsub) * D_ + ch * 8);
    *reinterpret_cast<s8*>(LQ + swz(wave * 8 + rsub, ch * 16)) = t0;
    *reinterpret_cast<s8*>(LQ + swz(wave * 8 + 4 + rsub, ch * 16)) = t1;
    __syncthreads();
    #pragma unroll
    for (int ms = 0; ms < 4; ms++) {
      f4 st = {0.f, 0.f, 0.f, 0.f};
      #pragma unroll
      for (int kk = 0; kk < 4; kk++) {
        s8 bq = *reinterpret_cast<const s8*>(LQ + swz(ms * 16 + c16, kk * 64 + quad * 16));
        st = mfma16(ak[kk], bq, st);
      }
      #pragma unroll
      for (int r = 0; r < 4; r++) sum[r] += exp2f(st[r] * CS);
    }
    __syncthreads();
  }
  #pragma unroll
  for (int mask = 1; mask < 16; mask <<= 1) {
    #pragma unroll
    for (int r = 0; r < 4; r++) sum[r] += __shfl_xor(sum[r], mask, 64);
  }
  if (c16 == 0) {
    f4 iv;
    #pragma unroll
    for (int r = 0; r < 4; r++) iv[r] = 1.f / sum[r];
    *reinterpret_cast<f4*>(inv + (long)b * N_ + nb + quad * 4) = iv;
  }
}

// Pass 2a v7 (round-8 verified, 154 us): 256 thr, 64m x 128d tile, 64-n chunks,
// 32x32x16 MFMA, KPV register-prefetch. NOTE: do NOT extend cross-barrier
// liveness here (r9's Vt hoist + split-K chains spilled -> 14x HBM fetch).
__global__ __launch_bounds__(256, 4) void attn_v7(const u16* __restrict__ q,
    const u16* __restrict__ kpv, const u16* __restrict__ vt,
    const float* __restrict__ inv, float* __restrict__ part,
    int lgns, int nslice) {
  __shared__ char LK[16384];
  __shared__ char LP[8192];
  const int tid = threadIdx.x;
  const int wave = tid >> 6, lane = tid & 63;
  const int l31 = lane & 31, hi = lane >> 5;
  const int bid = blockIdx.x;                    // b x mb(64) x ns
  const int ns = bid & ((1 << lgns) - 1);
  const int mb = (bid >> lgns) & 63;
  const int b = bid >> (lgns + 6);
  const int nt = wave & 1, mt = wave >> 1;       // S^T tile: 32n x 32m
  const int m_base = mb * 64;
  const int n_begin = ns * nslice;
  const int rsub = lane >> 4, ch = lane & 15;    // staging roles

  const u16* kpb = kpv + (long)b * N_ * D_;
  const u16* vtb = vt + (long)b * (long)D_ * N_;
  const float* invb = inv + (long)b * N_;

  s8 bq[8];                                      // Q B-frags: 8 ksteps (K=128)
  {
    const u16* qr = q + ((long)b * M_ + m_base + mt * 32 + l31) * D_ + hi * 8;
    #pragma unroll
    for (int kk = 0; kk < 8; kk++) bq[kk] = ld8(qr + kk * 16);
  }
  f16v acc[2];                                   // O: 2 m-tiles x wave's 32 d
  #pragma unroll
  for (int i = 0; i < 2; i++)
    #pragma unroll
    for (int r = 0; r < 16; r++) acc[i][r] = 0.f;

  // preload first KPV chunk into regs
  s8 tmp[4];
  #pragma unroll
  for (int i = 0; i < 4; i++)
    tmp[i] = ld8(kpb + (long)(n_begin + wave * 16 + i * 4 + rsub) * D_ + ch * 8);

  for (int n0 = n_begin; n0 < n_begin + nslice; n0 += 64) {
    // write staged KPV(i) -> LK
    #pragma unroll
    for (int i = 0; i < 4; i++)
      *reinterpret_cast<s8*>(LK + swz(wave * 16 + i * 4 + rsub, ch * 16)) = tmp[i];
    // prefetch KPV(i+1)
    {
      int nn = n0 + 64;
      if (nn >= n_begin + nslice) nn = n_begin;  // last iter: dummy (unused)
      #pragma unroll
      for (int i = 0; i < 4; i++)
        tmp[i] = ld8(kpb + (long)(nn + wave * 16 + i * 4 + rsub) * D_ + ch * 8);
    }
    __syncthreads();                             // LK ready; LP safe (PV(i-1) done)
    // ---- S^T: wave tile 32n(nt) x 32m(mt), K=128 ----
    {
      f16v st;
      #pragma unroll
      for (int r = 0; r < 16; r++) st[r] = 0.f;
      #pragma unroll
      for (int kk = 0; kk < 8; kk++) {
        s8 aK = *reinterpret_cast<const s8*>(
            LK + swz(nt * 32 + l31, kk * 32 + hi * 16));
        st = mfma32(aK, bq[kk], st);
      }
      // C: col=m (l31), row n = nt*32 + 8g + 4hi + r  (reg = g*4+r)
      #pragma unroll
      for (int g = 0; g < 4; g++) {
        const f4 ic = *reinterpret_cast<const f4*>(invb + n0 + nt * 32 + 8 * g + 4 * hi);
        us4 pk;
        #pragma unroll
        for (int r = 0; r < 4; r++)
          pk[r] = (u16)(__float_as_uint(exp2f(st[g * 4 + r] * CS) * ic[r]) >> 16);
        // LP: granule (4nt+g), row m = mt*32+l31, byte 8*hi
        *reinterpret_cast<us4*>(LP + (4 * nt + g) * 1024 + (mt * 32 + l31) * 16 + 8 * hi) = pk;
      }
    }
    __syncthreads();                             // LP ready; LK(i) reads done
    // ---- PV: wave owns 32 d (wave*32), both m-tiles, K=64 ----
    #pragma unroll
    for (int kk = 0; kk < 4; kk++) {
      s8 bv = ld8(vtb + (long)(wave * 32 + l31) * N_ + n0 + kk * 16 + hi * 8);
      #pragma unroll
      for (int i = 0; i < 2; i++) {
        s8 ap = *reinterpret_cast<const s8*>(
            LP + (2 * kk + hi) * 1024 + (i * 32 + l31) * 16);
        acc[i] = mfma32(ap, bv, acc[i]);
      }
    }
  }
  // store partial tile [64m][128d] f32; C: col=d, row m=(reg&3)+8*(reg>>2)+4*hi
  float* pt = part + (long)bid * 64 * 128;
  #pragma unroll
  for (int i = 0; i < 2; i++)
    #pragma unroll
    for (int g = 0; g < 4; g++)
      #pragma unroll
      for (int r = 0; r < 4; r++)
        pt[(i * 32 + g * 8 + 4 * hi + r) * 128 + wave * 32 + l31] = acc[i][g * 4 + r];
}

// Pass 2b: out = sum_ns partial + vfeat  (f32 out)
__global__ __launch_bounds__(256) void attn_reduce(const float* __restrict__ part,
    const float* __restrict__ vfeat, float* __restrict__ out, int nsplit) {
  const int g4 = blockIdx.x * 256 + threadIdx.x;     // 0 .. B*M*D/4-1
  const int b = g4 >> 17;                            // M*D/4 = 131072
  const int rem = g4 & 131071;
  const int m = rem >> 5;
  const int d4 = rem & 31;
  const int mb = m >> 6, mr = m & 63;
  const long base = ((long)(b * 64 + mb) * nsplit) * 8192 + mr * 128 + d4 * 4;
  f4 s = *reinterpret_cast<const f4*>(vfeat + (long)g4 * 4);
  for (int ns = 0; ns < nsplit; ns++)
    s += *reinterpret_cast<const f4*>(part + base + ns * 8192);
  *reinterpret_cast<f4*>(out + (long)g4 * 4) = s;
}

extern "C" void kernel_launch(void* const* d_in, const int* in_sizes, int n_in,
                              void* d_out, int out_size, void* d_ws, size_t ws_size,
                              hipStream_t stream) {
  const float* p_xyz  = (const float*)d_in[0];
  const float* v_xyz  = (const float*)d_in[1];
  const float* p_feat = (const float*)d_in[2];
  const float* v_feat = (const float*)d_in[3];
  const float* aW1 = (const float*)d_in[4],  *ab1 = (const float*)d_in[5];
  const float* aW2 = (const float*)d_in[6],  *ab2 = (const float*)d_in[7];
  const float* bW1 = (const float*)d_in[8],  *bb1 = (const float*)d_in[9];
  const float* bW2 = (const float*)d_in[10], *bb2 = (const float*)d_in[11];
  const float* oW1 = (const float*)d_in[12], *ob1 = (const float*)d_in[13];
  const float* oW2 = (const float*)d_in[14], *ob2 = (const float*)d_in[15];
  const float* dW1 = (const float*)d_in[16], *db1 = (const float*)d_in[17];
  const float* dW2 = (const float*)d_in[18], *db2 = (const float*)d_in[19];

  char* ws = (char*)d_ws;
  u16* wt    = (u16*)ws;                               // 7 * 16384 bf16 elems
  u16* aW1t  = wt + 0 * 16384;
  u16* aW2t  = wt + 1 * 16384;
  u16* bW1t  = wt + 2 * 16384;
  u16* bW2t  = wt + 3 * 16384;
  u16* oW1t  = wt + 4 * 16384;
  u16* oW2t  = wt + 5 * 16384;
  u16* dW2t  = wt + 6 * 16384;
  u16* qbuf  = (u16*)(ws + 262144);                    // B*M*D bf16 = 2 MB
  u16* kpvb  = (u16*)(ws + 2359296);                   // B*N*D bf16 = 8 MB
  u16* vtb   = (u16*)(ws + 10747904);                  // Vt = 8 MB
  float* invb = (float*)(ws + 19136512);               // B*N f32 = 128 KB
  float* partb = (float*)(ws + 19267584);              // nsplit * 4 MB

  const size_t part_off = 19267584;
  int lgns = (ws_size >= part_off + (size_t)8 * B_ * M_ * D_ * 4) ? 3 : 2;
  const int nsplit = 1 << lgns;
  const int nslice = N_ / nsplit;

  wtrans<<<dim3(7), dim3(256), 0, stream>>>(aW1, aW2, bW1, bW2, oW1, oW2, dW2, wt);
  mlp2q<<<dim3((B_ * M_) / 64), dim3(256), 0, stream>>>(v_feat, aW1t, ab1, aW2t, ab2, qbuf);
  kpv_omega<<<dim3((B_ * N_) / 64), dim3(256), 0, stream>>>(
      p_feat, p_xyz, v_xyz, bW1t, bb1, bW2t, bb2, dW1, db1, dW2t, db2,
      oW1t, ob1, oW2t, ob2, kpvb, vtb);
  colsum_v2<<<dim3(B_ * (N_ / 128)), dim3(512), 0, stream>>>(qbuf, kpvb, invb);
  attn_v7<<<dim3(B_ * 64 * nsplit), dim3(256), 0, stream>>>(qbuf, kpvb, vtb, invb, partb,
                                                            lgns, nslice);
  attn_reduce<<<dim3((B_ * M_ * D_ / 4) / 256), dim3(256), 0, stream>>>(partb, v_feat,
                                                                        (float*)d_out,
                                                                        nsplit);
}

// Round 11
// 370.946 us; speedup vs baseline: 1.2608x; 1.0474x over previous
//
#include <hip/hip_runtime.h>

#define B_ 2
#define N_ 16384
#define M_ 4096
#define D_ 128

typedef __attribute__((ext_vector_type(8))) short s8;     // 8 bf16 (4 VGPRs)
typedef __attribute__((ext_vector_type(4))) float f4;     // MFMA C/D + float4 loads
typedef __attribute__((ext_vector_type(16))) float f16v;  // 32x32 MFMA C/D
typedef __attribute__((ext_vector_type(4))) unsigned short us4;
typedef unsigned short u16;

__device__ __forceinline__ u16 f2b(float f) {   // RNE float->bf16
  unsigned int x = __float_as_uint(f);
  unsigned int r = x + 0x7fffu + ((x >> 16) & 1u);
  return (u16)(r >> 16);
}
__device__ __forceinline__ s8 ld8(const u16* p) {
  return *reinterpret_cast<const s8*>(p);
}
__device__ __forceinline__ s8 ldcvt8(const float* p) {
  f4 x = *reinterpret_cast<const f4*>(p);
  f4 y = *reinterpret_cast<const f4*>(p + 4);
  s8 r;
  r[0] = (short)f2b(x[0]); r[1] = (short)f2b(x[1]);
  r[2] = (short)f2b(x[2]); r[3] = (short)f2b(x[3]);
  r[4] = (short)f2b(y[0]); r[5] = (short)f2b(y[1]);
  r[6] = (short)f2b(y[2]); r[7] = (short)f2b(y[3]);
  return r;
}
__device__ __forceinline__ f4 mfma16(s8 a, s8 b, f4 c) {
  return __builtin_amdgcn_mfma_f32_16x16x32_bf16(a, b, c, 0, 0, 0);
}
__device__ __forceinline__ f16v mfma32(s8 a, s8 b, f16v c) {
  return __builtin_amdgcn_mfma_f32_32x32x16_bf16(a, b, c, 0, 0, 0);
}
// XOR-swizzled LDS offset for 256B rows. off = byte offset in row.
__device__ __forceinline__ int swz(int row, int off) {
  return (row << 8) + ((((off >> 4) ^ (row & 15)) << 4) | (off & 15));
}
// scale * log2(e): exp(s/sqrt(128)) == exp2(s * CS)
#define CS 0.1275174365f

// Transpose seven 128x128 f32 weight matrices into ws as bf16 Wt[n][k] (B-frags).
__global__ void wtrans(const float* a0, const float* a1, const float* a2, const float* a3,
                       const float* a4, const float* a5, const float* a6, u16* dst) {
  const float* s;
  switch (blockIdx.x) {
    case 0: s = a0; break; case 1: s = a1; break; case 2: s = a2; break;
    case 3: s = a3; break; case 4: s = a4; break; case 5: s = a5; break;
    default: s = a6; break;
  }
  u16* d = dst + blockIdx.x * 16384;
  for (int i = threadIdx.x; i < 16384; i += 256) {
    int r = i >> 7, c = i & 127;
    d[c * 128 + r] = f2b(s[i]);
  }
}

// Q MLP v2: 32 rows/block (grid 256 = 1/CU), wave (rowg, nsh) splits rows x cols.
__global__ __launch_bounds__(256) void mlp2q(const float* __restrict__ X,
    const u16* __restrict__ W1t, const float* __restrict__ b1,
    const u16* __restrict__ W2t, const float* __restrict__ b2,
    u16* __restrict__ out) {
  __shared__ u16 H[32][136];
  const int tid = threadIdx.x;
  const int wave = tid >> 6, lane = tid & 63;
  const int c16 = lane & 15, quad = lane >> 4;
  const int rowg = wave & 1, nsh = wave >> 1;
  const long row0 = (long)blockIdx.x * 32 + rowg * 16;

  s8 a[4];
  {
    const float* xr = X + (row0 + c16) * D_ + quad * 8;
    #pragma unroll
    for (int kk = 0; kk < 4; kk++) a[kk] = ldcvt8(xr + kk * 32);
  }
  #pragma unroll
  for (int ns = 0; ns < 4; ns++) {
    f4 acc = {0.f, 0.f, 0.f, 0.f};
    const int c = (nsh * 4 + ns) * 16 + c16;
    const u16* wr = W1t + (long)c * 128 + quad * 8;
    #pragma unroll
    for (int kk = 0; kk < 4; kk++) acc = mfma16(a[kk], ld8(wr + kk * 32), acc);
    const float bias = b1[c];
    #pragma unroll
    for (int r = 0; r < 4; r++) {
      float v = acc[r] + bias;
      H[rowg * 16 + quad * 4 + r][c] = f2b(v > 0.f ? v : 0.f);
    }
  }
  __syncthreads();
  s8 a2[4];
  #pragma unroll
  for (int kk = 0; kk < 4; kk++)
    a2[kk] = *reinterpret_cast<const s8*>(&H[rowg * 16 + c16][kk * 32 + quad * 8]);
  #pragma unroll
  for (int ns = 0; ns < 4; ns++) {
    f4 acc = {0.f, 0.f, 0.f, 0.f};
    const int c = (nsh * 4 + ns) * 16 + c16;
    const u16* wr = W2t + (long)c * 128 + quad * 8;
    #pragma unroll
    for (int kk = 0; kk < 4; kk++) acc = mfma16(a2[kk], ld8(wr + kk * 32), acc);
    const float bias = b2[c];
    #pragma unroll
    for (int r = 0; r < 4; r++)
      out[(row0 + quad * 4 + r) * D_ + c] = f2b(acc[r] + bias);
  }
}

// Fused kpv+vt v2: three H buffers, ONE barrier (was 5). All three hidden
// layers computed back-to-back (independent), then both layer-2 passes with
// 3 independent MFMA chains. Wave reads only its own 16 rows of each H.
__global__ __launch_bounds__(256) void kpv_omega(
    const float* __restrict__ pf, const float* __restrict__ pxyz, const float* __restrict__ vxyz,
    const u16* __restrict__ bW1t, const float* __restrict__ bb1,
    const u16* __restrict__ bW2t, const float* __restrict__ bb2,
    const float* __restrict__ dW1, const float* __restrict__ db1,
    const u16* __restrict__ dW2t, const float* __restrict__ db2,
    const u16* __restrict__ oW1t, const float* __restrict__ ob1,
    const u16* __restrict__ oW2t, const float* __restrict__ ob2,
    u16* __restrict__ kpv_out, u16* __restrict__ vt_out) {
  __shared__ u16 H1[64][136];                    // beta hidden
  __shared__ u16 H2[64][136];                    // delta hidden
  __shared__ u16 H3[64][136];                    // omega hidden
  const int tid = threadIdx.x;
  const int wave = tid >> 6, lane = tid & 63;
  const int c16 = lane & 15, quad = lane >> 4;
  const long row0 = (long)blockIdx.x * 64 + wave * 16;

  s8 a[4];
  {
    const float* xr = pf + (row0 + c16) * D_ + quad * 8;
    #pragma unroll
    for (int kk = 0; kk < 4; kk++) a[kk] = ldcvt8(xr + kk * 32);
  }
  // ---- beta L1 -> H1, omega L1 -> H3 (independent chains) ----
  #pragma unroll
  for (int ns = 0; ns < 8; ns++) {
    f4 accb = {0.f, 0.f, 0.f, 0.f}, acco = {0.f, 0.f, 0.f, 0.f};
    const int c = ns * 16 + c16;
    const u16* wrb = bW1t + (long)c * 128 + quad * 8;
    const u16* wro = oW1t + (long)c * 128 + quad * 8;
    #pragma unroll
    for (int kk = 0; kk < 4; kk++) {
      accb = mfma16(a[kk], ld8(wrb + kk * 32), accb);
      acco = mfma16(a[kk], ld8(wro + kk * 32), acco);
    }
    const float biasb = bb1[c], biaso = ob1[c];
    #pragma unroll
    for (int r = 0; r < 4; r++) {
      float vb = accb[r] + biasb;
      float vo = acco[r] + biaso;
      H1[wave * 16 + quad * 4 + r][c] = f2b(vb > 0.f ? vb : 0.f);
      H3[wave * 16 + quad * 4 + r][c] = f2b(vo > 0.f ? vo : 0.f);
    }
  }
  // ---- delta hidden (Din=3, VALU) -> H2 ----
  {
    const long bat = ((long)blockIdx.x * 64) / N_;
    const float vx0 = vxyz[bat * 3 + 0];
    const float vx1 = vxyz[bat * 3 + 1];
    const float vx2 = vxyz[bat * 3 + 2];
    for (int i = 0; i < 32; i++) {
      const int e = lane + 64 * i;
      const int rr = e >> 7, cc = e & 127;
      const long gr = row0 + rr;
      const float d0 = fabsf(pxyz[gr * 3 + 0] - vx0);
      const float d1 = fabsf(pxyz[gr * 3 + 1] - vx1);
      const float d2 = fabsf(pxyz[gr * 3 + 2] - vx2);
      float h = d0 * dW1[cc] + d1 * dW1[128 + cc] + d2 * dW1[256 + cc] + db1[cc];
      H2[wave * 16 + rr][cc] = f2b(h > 0.f ? h : 0.f);
    }
  }
  __syncthreads();                               // single fence: writes -> reads
  s8 ab[4], ad[4], ao[4];
  #pragma unroll
  for (int kk = 0; kk < 4; kk++) {
    ab[kk] = *reinterpret_cast<const s8*>(&H1[wave * 16 + c16][kk * 32 + quad * 8]);
    ad[kk] = *reinterpret_cast<const s8*>(&H2[wave * 16 + c16][kk * 32 + quad * 8]);
    ao[kk] = *reinterpret_cast<const s8*>(&H3[wave * 16 + c16][kk * 32 + quad * 8]);
  }
  #pragma unroll
  for (int ns = 0; ns < 8; ns++) {
    const int c = ns * 16 + c16;
    f4 acck = {0.f, 0.f, 0.f, 0.f};              // kpv = beta-L2 + delta-L2
    f4 accv = {0.f, 0.f, 0.f, 0.f};              // vt = omega-L2
    const u16* wrb = bW2t + (long)c * 128 + quad * 8;
    const u16* wrd = dW2t + (long)c * 128 + quad * 8;
    const u16* wro = oW2t + (long)c * 128 + quad * 8;
    #pragma unroll
    for (int kk = 0; kk < 4; kk++) {
      acck = mfma16(ab[kk], ld8(wrb + kk * 32), acck);
      acck = mfma16(ad[kk], ld8(wrd + kk * 32), acck);
      accv = mfma16(ao[kk], ld8(wro + kk * 32), accv);
    }
    const float biask = bb2[c] + db2[c];
    const float biasv = ob2[c];
    #pragma unroll
    for (int r = 0; r < 4; r++)
      kpv_out[(row0 + quad * 4 + r) * D_ + c] = f2b(acck[r] + biask);
    {
      const long g = row0 + quad * 4;
      const long bb = g >> 14;
      const long n = g & (N_ - 1);
      us4 pk;
      #pragma unroll
      for (int r = 0; r < 4; r++) pk[r] = f2b(accv[r] + biasv);
      *reinterpret_cast<us4*>(vt_out + bb * (long)128 * N_ + (long)c * N_ + n) = pk;
    }
  }
}

// Pass 1 v2b: round-8-verified body, m-split x2 (grid 512 = 2 blocks/CU).
// Writes raw column sums; recip_k combines the two halves.
__global__ __launch_bounds__(512, 6) void colsum_v2b(const u16* __restrict__ q,
    const u16* __restrict__ kpv, float* __restrict__ sums) {
  __shared__ char LQ[16384];                     // 64 m x 128 k bf16, swizzled
  const int tid = threadIdx.x;
  const int wave = tid >> 6, lane = tid & 63;
  const int c16 = lane & 15, quad = lane >> 4;
  const int mh = blockIdx.x & 1;
  const int nb = ((blockIdx.x >> 1) & 127) * 128 + wave * 16;
  const int b = blockIdx.x >> 8;
  const int rsub = lane >> 4, ch = lane & 15;

  s8 ak[4];
  {
    const u16* kr = kpv + ((long)b * N_ + nb + c16) * D_ + quad * 8;
    #pragma unroll
    for (int kk = 0; kk < 4; kk++) ak[kk] = ld8(kr + kk * 32);
  }
  f4 sum = {0.f, 0.f, 0.f, 0.f};
  const u16* qb = q + (long)b * M_ * D_ + (long)mh * (M_ / 2) * D_;

  for (int m0 = 0; m0 < M_ / 2; m0 += 64) {
    s8 t0 = ld8(qb + (long)(m0 + wave * 8 + rsub) * D_ + ch * 8);
    s8 t1 = ld8(qb + (long)(m0 + wave * 8 + 4 + rsub) * D_ + ch * 8);
    *reinterpret_cast<s8*>(LQ + swz(wave * 8 + rsub, ch * 16)) = t0;
    *reinterpret_cast<s8*>(LQ + swz(wave * 8 + 4 + rsub, ch * 16)) = t1;
    __syncthreads();
    #pragma unroll
    for (int ms = 0; ms < 4; ms++) {
      f4 st = {0.f, 0.f, 0.f, 0.f};
      #pragma unroll
      for (int kk = 0; kk < 4; kk++) {
        s8 bq = *reinterpret_cast<const s8*>(LQ + swz(ms * 16 + c16, kk * 64 + quad * 16));
        st = mfma16(ak[kk], bq, st);
      }
      #pragma unroll
      for (int r = 0; r < 4; r++) sum[r] += exp2f(st[r] * CS);
    }
    __syncthreads();
  }
  #pragma unroll
  for (int mask = 1; mask < 16; mask <<= 1) {
    #pragma unroll
    for (int r = 0; r < 4; r++) sum[r] += __shfl_xor(sum[r], mask, 64);
  }
  if (c16 == 0)
    *reinterpret_cast<f4*>(sums + (long)mh * (B_ * N_) + (long)b * N_ + nb + quad * 4) = sum;
}

// inv = 1 / (sum of the two m-split partials)
__global__ __launch_bounds__(256) void recip_k(const float* __restrict__ sums,
                                               float* __restrict__ inv) {
  const int i = blockIdx.x * 256 + threadIdx.x;  // 0 .. B*N-1
  inv[i] = 1.f / (sums[i] + sums[B_ * N_ + i]);
}

// Pass 2a v7 (round-8 verified, 154 us): 256 thr, 64m x 128d tile, 64-n chunks,
// 32x32x16 MFMA, KPV register-prefetch. NOTE: do NOT extend cross-barrier
// liveness here (r9's Vt hoist + split-K chains spilled -> 14x HBM fetch).
__global__ __launch_bounds__(256, 4) void attn_v7(const u16* __restrict__ q,
    const u16* __restrict__ kpv, const u16* __restrict__ vt,
    const float* __restrict__ inv, float* __restrict__ part,
    int lgns, int nslice) {
  __shared__ char LK[16384];
  __shared__ char LP[8192];
  const int tid = threadIdx.x;
  const int wave = tid >> 6, lane = tid & 63;
  const int l31 = lane & 31, hi = lane >> 5;
  const int bid = blockIdx.x;                    // b x mb(64) x ns
  const int ns = bid & ((1 << lgns) - 1);
  const int mb = (bid >> lgns) & 63;
  const int b = bid >> (lgns + 6);
  const int nt = wave & 1, mt = wave >> 1;       // S^T tile: 32n x 32m
  const int m_base = mb * 64;
  const int n_begin = ns * nslice;
  const int rsub = lane >> 4, ch = lane & 15;    // staging roles

  const u16* kpb = kpv + (long)b * N_ * D_;
  const u16* vtb = vt + (long)b * (long)D_ * N_;
  const float* invb = inv + (long)b * N_;

  s8 bq[8];                                      // Q B-frags: 8 ksteps (K=128)
  {
    const u16* qr = q + ((long)b * M_ + m_base + mt * 32 + l31) * D_ + hi * 8;
    #pragma unroll
    for (int kk = 0; kk < 8; kk++) bq[kk] = ld8(qr + kk * 16);
  }
  f16v acc[2];                                   // O: 2 m-tiles x wave's 32 d
  #pragma unroll
  for (int i = 0; i < 2; i++)
    #pragma unroll
    for (int r = 0; r < 16; r++) acc[i][r] = 0.f;

  // preload first KPV chunk into regs
  s8 tmp[4];
  #pragma unroll
  for (int i = 0; i < 4; i++)
    tmp[i] = ld8(kpb + (long)(n_begin + wave * 16 + i * 4 + rsub) * D_ + ch * 8);

  for (int n0 = n_begin; n0 < n_begin + nslice; n0 += 64) {
    // write staged KPV(i) -> LK
    #pragma unroll
    for (int i = 0; i < 4; i++)
      *reinterpret_cast<s8*>(LK + swz(wave * 16 + i * 4 + rsub, ch * 16)) = tmp[i];
    // prefetch KPV(i+1)
    {
      int nn = n0 + 64;
      if (nn >= n_begin + nslice) nn = n_begin;  // last iter: dummy (unused)
      #pragma unroll
      for (int i = 0; i < 4; i++)
        tmp[i] = ld8(kpb + (long)(nn + wave * 16 + i * 4 + rsub) * D_ + ch * 8);
    }
    __syncthreads();                             // LK ready; LP safe (PV(i-1) done)
    // ---- S^T: wave tile 32n(nt) x 32m(mt), K=128 ----
    {
      f16v st;
      #pragma unroll
      for (int r = 0; r < 16; r++) st[r] = 0.f;
      #pragma unroll
      for (int kk = 0; kk < 8; kk++) {
        s8 aK = *reinterpret_cast<const s8*>(
            LK + swz(nt * 32 + l31, kk * 32 + hi * 16));
        st = mfma32(aK, bq[kk], st);
      }
      // C: col=m (l31), row n = nt*32 + 8g + 4hi + r  (reg = g*4+r)
      #pragma unroll
      for (int g = 0; g < 4; g++) {
        const f4 ic = *reinterpret_cast<const f4*>(invb + n0 + nt * 32 + 8 * g + 4 * hi);
        us4 pk;
        #pragma unroll
        for (int r = 0; r < 4; r++)
          pk[r] = (u16)(__float_as_uint(exp2f(st[g * 4 + r] * CS) * ic[r]) >> 16);
        // LP: granule (4nt+g), row m = mt*32+l31, byte 8*hi
        *reinterpret_cast<us4*>(LP + (4 * nt + g) * 1024 + (mt * 32 + l31) * 16 + 8 * hi) = pk;
      }
    }
    __syncthreads();                             // LP ready; LK(i) reads done
    // ---- PV: wave owns 32 d (wave*32), both m-tiles, K=64 ----
    #pragma unroll
    for (int kk = 0; kk < 4; kk++) {
      s8 bv = ld8(vtb + (long)(wave * 32 + l31) * N_ + n0 + kk * 16 + hi * 8);
      #pragma unroll
      for (int i = 0; i < 2; i++) {
        s8 ap = *reinterpret_cast<const s8*>(
            LP + (2 * kk + hi) * 1024 + (i * 32 + l31) * 16);
        acc[i] = mfma32(ap, bv, acc[i]);
      }
    }
  }
  // store partial tile [64m][128d] f32; C: col=d, row m=(reg&3)+8*(reg>>2)+4*hi
  float* pt = part + (long)bid * 64 * 128;
  #pragma unroll
  for (int i = 0; i < 2; i++)
    #pragma unroll
    for (int g = 0; g < 4; g++)
      #pragma unroll
      for (int r = 0; r < 4; r++)
        pt[(i * 32 + g * 8 + 4 * hi + r) * 128 + wave * 32 + l31] = acc[i][g * 4 + r];
}

// Pass 2b: out = sum_ns partial + vfeat  (f32 out)
__global__ __launch_bounds__(256) void attn_reduce(const float* __restrict__ part,
    const float* __restrict__ vfeat, float* __restrict__ out, int nsplit) {
  const int g4 = blockIdx.x * 256 + threadIdx.x;     // 0 .. B*M*D/4-1
  const int b = g4 >> 17;                            // M*D/4 = 131072
  const int rem = g4 & 131071;
  const int m = rem >> 5;
  const int d4 = rem & 31;
  const int mb = m >> 6, mr = m & 63;
  const long base = ((long)(b * 64 + mb) * nsplit) * 8192 + mr * 128 + d4 * 4;
  f4 s = *reinterpret_cast<const f4*>(vfeat + (long)g4 * 4);
  for (int ns = 0; ns < nsplit; ns++)
    s += *reinterpret_cast<const f4*>(part + base + ns * 8192);
  *reinterpret_cast<f4*>(out + (long)g4 * 4) = s;
}

extern "C" void kernel_launch(void* const* d_in, const int* in_sizes, int n_in,
                              void* d_out, int out_size, void* d_ws, size_t ws_size,
                              hipStream_t stream) {
  const float* p_xyz  = (const float*)d_in[0];
  const float* v_xyz  = (const float*)d_in[1];
  const float* p_feat = (const float*)d_in[2];
  const float* v_feat = (const float*)d_in[3];
  const float* aW1 = (const float*)d_in[4],  *ab1 = (const float*)d_in[5];
  const float* aW2 = (const float*)d_in[6],  *ab2 = (const float*)d_in[7];
  const float* bW1 = (const float*)d_in[8],  *bb1 = (const float*)d_in[9];
  const float* bW2 = (const float*)d_in[10], *bb2 = (const float*)d_in[11];
  const float* oW1 = (const float*)d_in[12], *ob1 = (const float*)d_in[13];
  const float* oW2 = (const float*)d_in[14], *ob2 = (const float*)d_in[15];
  const float* dW1 = (const float*)d_in[16], *db1 = (const float*)d_in[17];
  const float* dW2 = (const float*)d_in[18], *db2 = (const float*)d_in[19];

  char* ws = (char*)d_ws;
  u16* wt    = (u16*)ws;                               // 7 * 16384 bf16 elems
  u16* aW1t  = wt + 0 * 16384;
  u16* aW2t  = wt + 1 * 16384;
  u16* bW1t  = wt + 2 * 16384;
  u16* bW2t  = wt + 3 * 16384;
  u16* oW1t  = wt + 4 * 16384;
  u16* oW2t  = wt + 5 * 16384;
  u16* dW2t  = wt + 6 * 16384;
  u16* qbuf  = (u16*)(ws + 262144);                    // B*M*D bf16 = 2 MB
  u16* kpvb  = (u16*)(ws + 2359296);                   // B*N*D bf16 = 8 MB
  u16* vtb   = (u16*)(ws + 10747904);                  // Vt = 8 MB
  float* invb = (float*)(ws + 19136512);               // B*N f32 = 128 KB
  float* partb = (float*)(ws + 19267584);              // nsplit * 4 MB
  float* sums  = partb;                                // 256 KB, consumed pre-attn

  const size_t part_off = 19267584;
  int lgns = 2;
  if (ws_size >= part_off + (size_t)16 * B_ * M_ * D_ * 4)      lgns = 4;
  else if (ws_size >= part_off + (size_t)8 * B_ * M_ * D_ * 4)  lgns = 3;
  const int nsplit = 1 << lgns;
  const int nslice = N_ / nsplit;

  wtrans<<<dim3(7), dim3(256), 0, stream>>>(aW1, aW2, bW1, bW2, oW1, oW2, dW2, wt);
  mlp2q<<<dim3((B_ * M_) / 32), dim3(256), 0, stream>>>(v_feat, aW1t, ab1, aW2t, ab2, qbuf);
  kpv_omega<<<dim3((B_ * N_) / 64), dim3(256), 0, stream>>>(
      p_feat, p_xyz, v_xyz, bW1t, bb1, bW2t, bb2, dW1, db1, dW2t, db2,
      oW1t, ob1, oW2t, ob2, kpvb, vtb);
  colsum_v2b<<<dim3(B_ * 128 * 2), dim3(512), 0, stream>>>(qbuf, kpvb, sums);
  recip_k<<<dim3((B_ * N_) / 256), dim3(256), 0, stream>>>(sums, invb);
  attn_v7<<<dim3(B_ * 64 * nsplit), dim3(256), 0, stream>>>(qbuf, kpvb, vtb, invb, partb,
                                                            lgns, nslice);
  attn_reduce<<<dim3((B_ * M_ * D_ / 4) / 256), dim3(256), 0, stream>>>(partb, v_feat,
                                                                        (float*)d_out,
                                                                        nsplit);
}

// Round 12
// 347.321 us; speedup vs baseline: 1.3466x; 1.0680x over previous
//
#include <hip/hip_runtime.h>

#define B_ 2
#define N_ 16384
#define M_ 4096
#define D_ 128

typedef __attribute__((ext_vector_type(8))) short s8;     // 8 bf16 (4 VGPRs)
typedef __attribute__((ext_vector_type(4))) float f4;     // MFMA C/D + float4 loads
typedef __attribute__((ext_vector_type(16))) float f16v;  // 32x32 MFMA C/D
typedef __attribute__((ext_vector_type(4))) unsigned short us4;
typedef unsigned short u16;

__device__ __forceinline__ u16 f2b(float f) {   // RNE float->bf16
  unsigned int x = __float_as_uint(f);
  unsigned int r = x + 0x7fffu + ((x >> 16) & 1u);
  return (u16)(r >> 16);
}
__device__ __forceinline__ s8 ld8(const u16* p) {
  return *reinterpret_cast<const s8*>(p);
}
__device__ __forceinline__ s8 ldcvt8(const float* p) {
  f4 x = *reinterpret_cast<const f4*>(p);
  f4 y = *reinterpret_cast<const f4*>(p + 4);
  s8 r;
  r[0] = (short)f2b(x[0]); r[1] = (short)f2b(x[1]);
  r[2] = (short)f2b(x[2]); r[3] = (short)f2b(x[3]);
  r[4] = (short)f2b(y[0]); r[5] = (short)f2b(y[1]);
  r[6] = (short)f2b(y[2]); r[7] = (short)f2b(y[3]);
  return r;
}
__device__ __forceinline__ f4 mfma16(s8 a, s8 b, f4 c) {
  return __builtin_amdgcn_mfma_f32_16x16x32_bf16(a, b, c, 0, 0, 0);
}
__device__ __forceinline__ f16v mfma32(s8 a, s8 b, f16v c) {
  return __builtin_amdgcn_mfma_f32_32x32x16_bf16(a, b, c, 0, 0, 0);
}
// XOR-swizzled LDS offset for 256B rows. off = byte offset in row.
__device__ __forceinline__ int swz(int row, int off) {
  return (row << 8) + ((((off >> 4) ^ (row & 15)) << 4) | (off & 15));
}
// scale * log2(e): exp(s/sqrt(128)) == exp2(s * CS)
#define CS 0.1275174365f

// Transpose seven 128x128 f32 weight matrices into ws as bf16 Wt[n][k] (B-frags).
__global__ void wtrans(const float* a0, const float* a1, const float* a2, const float* a3,
                       const float* a4, const float* a5, const float* a6, u16* dst) {
  const float* s;
  switch (blockIdx.x) {
    case 0: s = a0; break; case 1: s = a1; break; case 2: s = a2; break;
    case 3: s = a3; break; case 4: s = a4; break; case 5: s = a5; break;
    default: s = a6; break;
  }
  u16* d = dst + blockIdx.x * 16384;
  for (int i = threadIdx.x; i < 16384; i += 256) {
    int r = i >> 7, c = i & 127;
    d[c * 128 + r] = f2b(s[i]);
  }
}

// Q MLP v2: 32 rows/block (grid 256), wave (rowg, nsh) splits rows x cols.
__global__ __launch_bounds__(256) void mlp2q(const float* __restrict__ X,
    const u16* __restrict__ W1t, const float* __restrict__ b1,
    const u16* __restrict__ W2t, const float* __restrict__ b2,
    u16* __restrict__ out) {
  __shared__ u16 H[32][136];
  const int tid = threadIdx.x;
  const int wave = tid >> 6, lane = tid & 63;
  const int c16 = lane & 15, quad = lane >> 4;
  const int rowg = wave & 1, nsh = wave >> 1;
  const long row0 = (long)blockIdx.x * 32 + rowg * 16;

  s8 a[4];
  {
    const float* xr = X + (row0 + c16) * D_ + quad * 8;
    #pragma unroll
    for (int kk = 0; kk < 4; kk++) a[kk] = ldcvt8(xr + kk * 32);
  }
  #pragma unroll
  for (int ns = 0; ns < 4; ns++) {
    f4 acc = {0.f, 0.f, 0.f, 0.f};
    const int c = (nsh * 4 + ns) * 16 + c16;
    const u16* wr = W1t + (long)c * 128 + quad * 8;
    #pragma unroll
    for (int kk = 0; kk < 4; kk++) acc = mfma16(a[kk], ld8(wr + kk * 32), acc);
    const float bias = b1[c];
    #pragma unroll
    for (int r = 0; r < 4; r++) {
      float v = acc[r] + bias;
      H[rowg * 16 + quad * 4 + r][c] = f2b(v > 0.f ? v : 0.f);
    }
  }
  __syncthreads();
  s8 a2[4];
  #pragma unroll
  for (int kk = 0; kk < 4; kk++)
    a2[kk] = *reinterpret_cast<const s8*>(&H[rowg * 16 + c16][kk * 32 + quad * 8]);
  #pragma unroll
  for (int ns = 0; ns < 4; ns++) {
    f4 acc = {0.f, 0.f, 0.f, 0.f};
    const int c = (nsh * 4 + ns) * 16 + c16;
    const u16* wr = W2t + (long)c * 128 + quad * 8;
    #pragma unroll
    for (int kk = 0; kk < 4; kk++) acc = mfma16(a2[kk], ld8(wr + kk * 32), acc);
    const float bias = b2[c];
    #pragma unroll
    for (int r = 0; r < 4; r++)
      out[(row0 + quad * 4 + r) * D_ + c] = f2b(acc[r] + bias);
  }
}

// Fused kpv+vt v2: three H buffers, ONE barrier. (round-11 verified)
__global__ __launch_bounds__(256) void kpv_omega(
    const float* __restrict__ pf, const float* __restrict__ pxyz, const float* __restrict__ vxyz,
    const u16* __restrict__ bW1t, const float* __restrict__ bb1,
    const u16* __restrict__ bW2t, const float* __restrict__ bb2,
    const float* __restrict__ dW1, const float* __restrict__ db1,
    const u16* __restrict__ dW2t, const float* __restrict__ db2,
    const u16* __restrict__ oW1t, const float* __restrict__ ob1,
    const u16* __restrict__ oW2t, const float* __restrict__ ob2,
    u16* __restrict__ kpv_out, u16* __restrict__ vt_out) {
  __shared__ u16 H1[64][136];                    // beta hidden
  __shared__ u16 H2[64][136];                    // delta hidden
  __shared__ u16 H3[64][136];                    // omega hidden
  const int tid = threadIdx.x;
  const int wave = tid >> 6, lane = tid & 63;
  const int c16 = lane & 15, quad = lane >> 4;
  const long row0 = (long)blockIdx.x * 64 + wave * 16;

  s8 a[4];
  {
    const float* xr = pf + (row0 + c16) * D_ + quad * 8;
    #pragma unroll
    for (int kk = 0; kk < 4; kk++) a[kk] = ldcvt8(xr + kk * 32);
  }
  #pragma unroll
  for (int ns = 0; ns < 8; ns++) {
    f4 accb = {0.f, 0.f, 0.f, 0.f}, acco = {0.f, 0.f, 0.f, 0.f};
    const int c = ns * 16 + c16;
    const u16* wrb = bW1t + (long)c * 128 + quad * 8;
    const u16* wro = oW1t + (long)c * 128 + quad * 8;
    #pragma unroll
    for (int kk = 0; kk < 4; kk++) {
      accb = mfma16(a[kk], ld8(wrb + kk * 32), accb);
      acco = mfma16(a[kk], ld8(wro + kk * 32), acco);
    }
    const float biasb = bb1[c], biaso = ob1[c];
    #pragma unroll
    for (int r = 0; r < 4; r++) {
      float vb = accb[r] + biasb;
      float vo = acco[r] + biaso;
      H1[wave * 16 + quad * 4 + r][c] = f2b(vb > 0.f ? vb : 0.f);
      H3[wave * 16 + quad * 4 + r][c] = f2b(vo > 0.f ? vo : 0.f);
    }
  }
  {
    const long bat = ((long)blockIdx.x * 64) / N_;
    const float vx0 = vxyz[bat * 3 + 0];
    const float vx1 = vxyz[bat * 3 + 1];
    const float vx2 = vxyz[bat * 3 + 2];
    for (int i = 0; i < 32; i++) {
      const int e = lane + 64 * i;
      const int rr = e >> 7, cc = e & 127;
      const long gr = row0 + rr;
      const float d0 = fabsf(pxyz[gr * 3 + 0] - vx0);
      const float d1 = fabsf(pxyz[gr * 3 + 1] - vx1);
      const float d2 = fabsf(pxyz[gr * 3 + 2] - vx2);
      float h = d0 * dW1[cc] + d1 * dW1[128 + cc] + d2 * dW1[256 + cc] + db1[cc];
      H2[wave * 16 + rr][cc] = f2b(h > 0.f ? h : 0.f);
    }
  }
  __syncthreads();                               // single fence: writes -> reads
  s8 ab[4], ad[4], ao[4];
  #pragma unroll
  for (int kk = 0; kk < 4; kk++) {
    ab[kk] = *reinterpret_cast<const s8*>(&H1[wave * 16 + c16][kk * 32 + quad * 8]);
    ad[kk] = *reinterpret_cast<const s8*>(&H2[wave * 16 + c16][kk * 32 + quad * 8]);
    ao[kk] = *reinterpret_cast<const s8*>(&H3[wave * 16 + c16][kk * 32 + quad * 8]);
  }
  #pragma unroll
  for (int ns = 0; ns < 8; ns++) {
    const int c = ns * 16 + c16;
    f4 acck = {0.f, 0.f, 0.f, 0.f};              // kpv = beta-L2 + delta-L2
    f4 accv = {0.f, 0.f, 0.f, 0.f};              // vt = omega-L2
    const u16* wrb = bW2t + (long)c * 128 + quad * 8;
    const u16* wrd = dW2t + (long)c * 128 + quad * 8;
    const u16* wro = oW2t + (long)c * 128 + quad * 8;
    #pragma unroll
    for (int kk = 0; kk < 4; kk++) {
      acck = mfma16(ab[kk], ld8(wrb + kk * 32), acck);
      acck = mfma16(ad[kk], ld8(wrd + kk * 32), acck);
      accv = mfma16(ao[kk], ld8(wro + kk * 32), accv);
    }
    const float biask = bb2[c] + db2[c];
    const float biasv = ob2[c];
    #pragma unroll
    for (int r = 0; r < 4; r++)
      kpv_out[(row0 + quad * 4 + r) * D_ + c] = f2b(acck[r] + biask);
    {
      const long g = row0 + quad * 4;
      const long bb = g >> 14;
      const long n = g & (N_ - 1);
      us4 pk;
      #pragma unroll
      for (int r = 0; r < 4; r++) pk[r] = f2b(accv[r] + biasv);
      *reinterpret_cast<us4*>(vt_out + bb * (long)128 * N_ + (long)c * N_ + n) = pk;
    }
  }
}

// Pass 1 v2c: round-8-verified body, m-split x4 (grid 1024 = 4 blocks/CU).
// Writes raw column sums; recip_k combines 4 slices into -log2(sum).
__global__ __launch_bounds__(512, 6) void colsum_v2c(const u16* __restrict__ q,
    const u16* __restrict__ kpv, float* __restrict__ sums) {
  __shared__ char LQ[16384];                     // 64 m x 128 k bf16, swizzled
  const int tid = threadIdx.x;
  const int wave = tid >> 6, lane = tid & 63;
  const int c16 = lane & 15, quad = lane >> 4;
  const int mh = blockIdx.x & 3;
  const int nb = ((blockIdx.x >> 2) & 127) * 128 + wave * 16;
  const int b = blockIdx.x >> 9;
  const int rsub = lane >> 4, ch = lane & 15;

  s8 ak[4];
  {
    const u16* kr = kpv + ((long)b * N_ + nb + c16) * D_ + quad * 8;
    #pragma unroll
    for (int kk = 0; kk < 4; kk++) ak[kk] = ld8(kr + kk * 32);
  }
  f4 sum = {0.f, 0.f, 0.f, 0.f};
  const u16* qb = q + (long)b * M_ * D_ + (long)mh * (M_ / 4) * D_;

  for (int m0 = 0; m0 < M_ / 4; m0 += 64) {
    s8 t0 = ld8(qb + (long)(m0 + wave * 8 + rsub) * D_ + ch * 8);
    s8 t1 = ld8(qb + (long)(m0 + wave * 8 + 4 + rsub) * D_ + ch * 8);
    *reinterpret_cast<s8*>(LQ + swz(wave * 8 + rsub, ch * 16)) = t0;
    *reinterpret_cast<s8*>(LQ + swz(wave * 8 + 4 + rsub, ch * 16)) = t1;
    __syncthreads();
    #pragma unroll
    for (int ms = 0; ms < 4; ms++) {
      f4 st = {0.f, 0.f, 0.f, 0.f};
      #pragma unroll
      for (int kk = 0; kk < 4; kk++) {
        s8 bq = *reinterpret_cast<const s8*>(LQ + swz(ms * 16 + c16, kk * 64 + quad * 16));
        st = mfma16(ak[kk], bq, st);
      }
      #pragma unroll
      for (int r = 0; r < 4; r++) sum[r] += exp2f(st[r] * CS);
    }
    __syncthreads();
  }
  #pragma unroll
  for (int mask = 1; mask < 16; mask <<= 1) {
    #pragma unroll
    for (int r = 0; r < 4; r++) sum[r] += __shfl_xor(sum[r], mask, 64);
  }
  if (c16 == 0)
    *reinterpret_cast<f4*>(sums + (long)mh * (B_ * N_) + (long)b * N_ + nb + quad * 4) = sum;
}

// l2ic = -log2(sum of the four m-split partials): folded into exp2 in attn.
__global__ __launch_bounds__(256) void recip_k(const float* __restrict__ sums,
                                               float* __restrict__ l2ic) {
  const int i = blockIdx.x * 256 + threadIdx.x;  // 0 .. B*N-1
  const float s = sums[i] + sums[B_ * N_ + i] + sums[2 * B_ * N_ + i]
                + sums[3 * B_ * N_ + i];
  l2ic[i] = -log2f(s);
}

// Pass 2a v7 (round-8 verified, 154 us) + l2ic fold: P = exp2(s*CS + l2ic).
// NOTE: do NOT extend cross-barrier liveness here (r9 spill: 14x HBM fetch).
__global__ __launch_bounds__(256, 4) void attn_v7(const u16* __restrict__ q,
    const u16* __restrict__ kpv, const u16* __restrict__ vt,
    const float* __restrict__ l2ic, float* __restrict__ part,
    int lgns, int nslice) {
  __shared__ char LK[16384];
  __shared__ char LP[8192];
  const int tid = threadIdx.x;
  const int wave = tid >> 6, lane = tid & 63;
  const int l31 = lane & 31, hi = lane >> 5;
  const int bid = blockIdx.x;                    // b x mb(64) x ns
  const int ns = bid & ((1 << lgns) - 1);
  const int mb = (bid >> lgns) & 63;
  const int b = bid >> (lgns + 6);
  const int nt = wave & 1, mt = wave >> 1;       // S^T tile: 32n x 32m
  const int m_base = mb * 64;
  const int n_begin = ns * nslice;
  const int rsub = lane >> 4, ch = lane & 15;    // staging roles

  const u16* kpb = kpv + (long)b * N_ * D_;
  const u16* vtb = vt + (long)b * (long)D_ * N_;
  const float* l2b = l2ic + (long)b * N_;

  s8 bq[8];                                      // Q B-frags: 8 ksteps (K=128)
  {
    const u16* qr = q + ((long)b * M_ + m_base + mt * 32 + l31) * D_ + hi * 8;
    #pragma unroll
    for (int kk = 0; kk < 8; kk++) bq[kk] = ld8(qr + kk * 16);
  }
  f16v acc[2];                                   // O: 2 m-tiles x wave's 32 d
  #pragma unroll
  for (int i = 0; i < 2; i++)
    #pragma unroll
    for (int r = 0; r < 16; r++) acc[i][r] = 0.f;

  // preload first KPV chunk into regs
  s8 tmp[4];
  #pragma unroll
  for (int i = 0; i < 4; i++)
    tmp[i] = ld8(kpb + (long)(n_begin + wave * 16 + i * 4 + rsub) * D_ + ch * 8);

  for (int n0 = n_begin; n0 < n_begin + nslice; n0 += 64) {
    // write staged KPV(i) -> LK
    #pragma unroll
    for (int i = 0; i < 4; i++)
      *reinterpret_cast<s8*>(LK + swz(wave * 16 + i * 4 + rsub, ch * 16)) = tmp[i];
    // prefetch KPV(i+1)
    {
      int nn = n0 + 64;
      if (nn >= n_begin + nslice) nn = n_begin;  // last iter: dummy (unused)
      #pragma unroll
      for (int i = 0; i < 4; i++)
        tmp[i] = ld8(kpb + (long)(nn + wave * 16 + i * 4 + rsub) * D_ + ch * 8);
    }
    __syncthreads();                             // LK ready; LP safe (PV(i-1) done)
    // ---- S^T: wave tile 32n(nt) x 32m(mt), K=128 ----
    {
      f16v st;
      #pragma unroll
      for (int r = 0; r < 16; r++) st[r] = 0.f;
      #pragma unroll
      for (int kk = 0; kk < 8; kk++) {
        s8 aK = *reinterpret_cast<const s8*>(
            LK + swz(nt * 32 + l31, kk * 32 + hi * 16));
        st = mfma32(aK, bq[kk], st);
      }
      // C: col=m (l31), row n = nt*32 + 8g + 4hi + r  (reg = g*4+r)
      #pragma unroll
      for (int g = 0; g < 4; g++) {
        const f4 l2 = *reinterpret_cast<const f4*>(l2b + n0 + nt * 32 + 8 * g + 4 * hi);
        us4 pk;
        #pragma unroll
        for (int r = 0; r < 4; r++)
          pk[r] = (u16)(__float_as_uint(exp2f(fmaf(st[g * 4 + r], CS, l2[r]))) >> 16);
        // LP: granule (4nt+g), row m = mt*32+l31, byte 8*hi
        *reinterpret_cast<us4*>(LP + (4 * nt + g) * 1024 + (mt * 32 + l31) * 16 + 8 * hi) = pk;
      }
    }
    __syncthreads();                             // LP ready; LK(i) reads done
    // ---- PV: wave owns 32 d (wave*32), both m-tiles, K=64 ----
    #pragma unroll
    for (int kk = 0; kk < 4; kk++) {
      s8 bv = ld8(vtb + (long)(wave * 32 + l31) * N_ + n0 + kk * 16 + hi * 8);
      #pragma unroll
      for (int i = 0; i < 2; i++) {
        s8 ap = *reinterpret_cast<const s8*>(
            LP + (2 * kk + hi) * 1024 + (i * 32 + l31) * 16);
        acc[i] = mfma32(ap, bv, acc[i]);
      }
    }
  }
  // store partial tile [64m][128d] f32; C: col=d, row m=(reg&3)+8*(reg>>2)+4*hi
  float* pt = part + (long)bid * 64 * 128;
  #pragma unroll
  for (int i = 0; i < 2; i++)
    #pragma unroll
    for (int g = 0; g < 4; g++)
      #pragma unroll
      for (int r = 0; r < 4; r++)
        pt[(i * 32 + g * 8 + 4 * hi + r) * 128 + wave * 32 + l31] = acc[i][g * 4 + r];
}

// Pass 2b: out = sum_ns partial + vfeat  (f32 out)
__global__ __launch_bounds__(256) void attn_reduce(const float* __restrict__ part,
    const float* __restrict__ vfeat, float* __restrict__ out, int nsplit) {
  const int g4 = blockIdx.x * 256 + threadIdx.x;     // 0 .. B*M*D/4-1
  const int b = g4 >> 17;                            // M*D/4 = 131072
  const int rem = g4 & 131071;
  const int m = rem >> 5;
  const int d4 = rem & 31;
  const int mb = m >> 6, mr = m & 63;
  const long base = ((long)(b * 64 + mb) * nsplit) * 8192 + mr * 128 + d4 * 4;
  f4 s = *reinterpret_cast<const f4*>(vfeat + (long)g4 * 4);
  for (int ns = 0; ns < nsplit; ns++)
    s += *reinterpret_cast<const f4*>(part + base + ns * 8192);
  *reinterpret_cast<f4*>(out + (long)g4 * 4) = s;
}

extern "C" void kernel_launch(void* const* d_in, const int* in_sizes, int n_in,
                              void* d_out, int out_size, void* d_ws, size_t ws_size,
                              hipStream_t stream) {
  const float* p_xyz  = (const float*)d_in[0];
  const float* v_xyz  = (const float*)d_in[1];
  const float* p_feat = (const float*)d_in[2];
  const float* v_feat = (const float*)d_in[3];
  const float* aW1 = (const float*)d_in[4],  *ab1 = (const float*)d_in[5];
  const float* aW2 = (const float*)d_in[6],  *ab2 = (const float*)d_in[7];
  const float* bW1 = (const float*)d_in[8],  *bb1 = (const float*)d_in[9];
  const float* bW2 = (const float*)d_in[10], *bb2 = (const float*)d_in[11];
  const float* oW1 = (const float*)d_in[12], *ob1 = (const float*)d_in[13];
  const float* oW2 = (const float*)d_in[14], *ob2 = (const float*)d_in[15];
  const float* dW1 = (const float*)d_in[16], *db1 = (const float*)d_in[17];
  const float* dW2 = (const float*)d_in[18], *db2 = (const float*)d_in[19];

  char* ws = (char*)d_ws;
  u16* wt    = (u16*)ws;                               // 7 * 16384 bf16 elems
  u16* aW1t  = wt + 0 * 16384;
  u16* aW2t  = wt + 1 * 16384;
  u16* bW1t  = wt + 2 * 16384;
  u16* bW2t  = wt + 3 * 16384;
  u16* oW1t  = wt + 4 * 16384;
  u16* oW2t  = wt + 5 * 16384;
  u16* dW2t  = wt + 6 * 16384;
  u16* qbuf  = (u16*)(ws + 262144);                    // B*M*D bf16 = 2 MB
  u16* kpvb  = (u16*)(ws + 2359296);                   // B*N*D bf16 = 8 MB
  u16* vtb   = (u16*)(ws + 10747904);                  // Vt = 8 MB
  float* invb = (float*)(ws + 19136512);               // B*N f32 = 128 KB (l2ic)
  float* partb = (float*)(ws + 19267584);              // nsplit * 4 MB
  float* sums  = partb;                                // 512 KB, consumed pre-attn

  const size_t part_off = 19267584;
  int lgns = (ws_size >= part_off + (size_t)8 * B_ * M_ * D_ * 4) ? 3 : 2;
  const int nsplit = 1 << lgns;                        // capped at 8 (16 regressed)
  const int nslice = N_ / nsplit;

  wtrans<<<dim3(7), dim3(256), 0, stream>>>(aW1, aW2, bW1, bW2, oW1, oW2, dW2, wt);
  mlp2q<<<dim3((B_ * M_) / 32), dim3(256), 0, stream>>>(v_feat, aW1t, ab1, aW2t, ab2, qbuf);
  kpv_omega<<<dim3((B_ * N_) / 64), dim3(256), 0, stream>>>(
      p_feat, p_xyz, v_xyz, bW1t, bb1, bW2t, bb2, dW1, db1, dW2t, db2,
      oW1t, ob1, oW2t, ob2, kpvb, vtb);
  colsum_v2c<<<dim3(B_ * 128 * 4), dim3(512), 0, stream>>>(qbuf, kpvb, sums);
  recip_k<<<dim3((B_ * N_) / 256), dim3(256), 0, stream>>>(sums, invb);
  attn_v7<<<dim3(B_ * 64 * nsplit), dim3(256), 0, stream>>>(qbuf, kpvb, vtb, invb, partb,
                                                            lgns, nslice);
  attn_reduce<<<dim3((B_ * M_ * D_ / 4) / 256), dim3(256), 0, stream>>>(partb, v_feat,
                                                                        (float*)d_out,
                                                                        nsplit);
}

// Round 13
// 325.076 us; speedup vs baseline: 1.4388x; 1.0684x over previous
//
#include <hip/hip_runtime.h>

#define B_ 2
#define N_ 16384
#define M_ 4096
#define D_ 128

typedef __attribute__((ext_vector_type(8))) short s8;     // 8 bf16 (4 VGPRs)
typedef __attribute__((ext_vector_type(4))) float f4;     // MFMA C/D + float4 loads
typedef __attribute__((ext_vector_type(16))) float f16v;  // 32x32 MFMA C/D
typedef __attribute__((ext_vector_type(4))) unsigned short us4;
typedef unsigned short u16;

__device__ __forceinline__ u16 f2b(float f) {   // RNE float->bf16
  unsigned int x = __float_as_uint(f);
  unsigned int r = x + 0x7fffu + ((x >> 16) & 1u);
  return (u16)(r >> 16);
}
__device__ __forceinline__ s8 ld8(const u16* p) {
  return *reinterpret_cast<const s8*>(p);
}
__device__ __forceinline__ s8 ldcvt8(const float* p) {
  f4 x = *reinterpret_cast<const f4*>(p);
  f4 y = *reinterpret_cast<const f4*>(p + 4);
  s8 r;
  r[0] = (short)f2b(x[0]); r[1] = (short)f2b(x[1]);
  r[2] = (short)f2b(x[2]); r[3] = (short)f2b(x[3]);
  r[4] = (short)f2b(y[0]); r[5] = (short)f2b(y[1]);
  r[6] = (short)f2b(y[2]); r[7] = (short)f2b(y[3]);
  return r;
}
__device__ __forceinline__ f4 mfma16(s8 a, s8 b, f4 c) {
  return __builtin_amdgcn_mfma_f32_16x16x32_bf16(a, b, c, 0, 0, 0);
}
__device__ __forceinline__ f16v mfma32(s8 a, s8 b, f16v c) {
  return __builtin_amdgcn_mfma_f32_32x32x16_bf16(a, b, c, 0, 0, 0);
}
// XOR-swizzled LDS offset for 256B rows. off = byte offset in row.
__device__ __forceinline__ int swz(int row, int off) {
  return (row << 8) + ((((off >> 4) ^ (row & 15)) << 4) | (off & 15));
}
// scale * log2(e): exp(s/sqrt(128)) == exp2(s * CS)
#define CS 0.1275174365f

// Transpose seven 128x128 f32 weight matrices into ws as bf16 Wt[n][k].
// 112 blocks: block (mat, part) writes output slice part*1024..+1023 coalesced.
__global__ __launch_bounds__(256) void wtrans(
    const float* a0, const float* a1, const float* a2, const float* a3,
    const float* a4, const float* a5, const float* a6, u16* dst) {
  const int mat = blockIdx.x >> 4, part = blockIdx.x & 15;
  const float* s;
  switch (mat) {
    case 0: s = a0; break; case 1: s = a1; break; case 2: s = a2; break;
    case 3: s = a3; break; case 4: s = a4; break; case 5: s = a5; break;
    default: s = a6; break;
  }
  u16* d = dst + mat * 16384 + part * 1024;
  const int o0 = part * 1024;
  for (int i = threadIdx.x; i < 1024; i += 256) {
    const int o = o0 + i;
    const int c = o >> 7, r = o & 127;
    d[i] = f2b(s[r * 128 + c]);
  }
}

// Fused MLPs, one launch (r12 bodies unchanged):
//  blocks [0,256):   Q = alpha-MLP(v_feat)            -> qbuf
//  blocks [256,768): kpv = beta+delta MLPs, vt = omega -> kpvb / vtb
__global__ __launch_bounds__(256) void mlps(
    const float* __restrict__ vfeat,
    const u16* __restrict__ aW1t, const float* __restrict__ ab1,
    const u16* __restrict__ aW2t, const float* __restrict__ ab2,
    u16* __restrict__ qbuf,
    const float* __restrict__ pf, const float* __restrict__ pxyz,
    const float* __restrict__ vxyz,
    const u16* __restrict__ bW1t, const float* __restrict__ bb1,
    const u16* __restrict__ bW2t, const float* __restrict__ bb2,
    const float* __restrict__ dW1, const float* __restrict__ db1,
    const u16* __restrict__ dW2t, const float* __restrict__ db2,
    const u16* __restrict__ oW1t, const float* __restrict__ ob1,
    const u16* __restrict__ oW2t, const float* __restrict__ ob2,
    u16* __restrict__ kpv_out, u16* __restrict__ vt_out) {
  __shared__ u16 H1[64][136];
  __shared__ u16 H2[64][136];
  __shared__ u16 H3[64][136];
  const int tid = threadIdx.x;
  const int wave = tid >> 6, lane = tid & 63;
  const int c16 = lane & 15, quad = lane >> 4;

  if (blockIdx.x < 256) {
    // ---------------- Q path: 32 rows/block ----------------
    const int rowg = wave & 1, nsh = wave >> 1;
    const long row0 = (long)blockIdx.x * 32 + rowg * 16;
    s8 a[4];
    {
      const float* xr = vfeat + (row0 + c16) * D_ + quad * 8;
      #pragma unroll
      for (int kk = 0; kk < 4; kk++) a[kk] = ldcvt8(xr + kk * 32);
    }
    #pragma unroll
    for (int ns = 0; ns < 4; ns++) {
      f4 acc = {0.f, 0.f, 0.f, 0.f};
      const int c = (nsh * 4 + ns) * 16 + c16;
      const u16* wr = aW1t + (long)c * 128 + quad * 8;
      #pragma unroll
      for (int kk = 0; kk < 4; kk++) acc = mfma16(a[kk], ld8(wr + kk * 32), acc);
      const float bias = ab1[c];
      #pragma unroll
      for (int r = 0; r < 4; r++) {
        float v = acc[r] + bias;
        H1[rowg * 16 + quad * 4 + r][c] = f2b(v > 0.f ? v : 0.f);
      }
    }
    __syncthreads();
    s8 a2[4];
    #pragma unroll
    for (int kk = 0; kk < 4; kk++)
      a2[kk] = *reinterpret_cast<const s8*>(&H1[rowg * 16 + c16][kk * 32 + quad * 8]);
    #pragma unroll
    for (int ns = 0; ns < 4; ns++) {
      f4 acc = {0.f, 0.f, 0.f, 0.f};
      const int c = (nsh * 4 + ns) * 16 + c16;
      const u16* wr = aW2t + (long)c * 128 + quad * 8;
      #pragma unroll
      for (int kk = 0; kk < 4; kk++) acc = mfma16(a2[kk], ld8(wr + kk * 32), acc);
      const float bias = ab2[c];
      #pragma unroll
      for (int r = 0; r < 4; r++)
        qbuf[(row0 + quad * 4 + r) * D_ + c] = f2b(acc[r] + bias);
    }
    return;
  }
  // ---------------- kpv + vt path: 64 rows/block ----------------
  const int bx = blockIdx.x - 256;
  const long row0 = (long)bx * 64 + wave * 16;
  s8 a[4];
  {
    const float* xr = pf + (row0 + c16) * D_ + quad * 8;
    #pragma unroll
    for (int kk = 0; kk < 4; kk++) a[kk] = ldcvt8(xr + kk * 32);
  }
  #pragma unroll
  for (int ns = 0; ns < 8; ns++) {
    f4 accb = {0.f, 0.f, 0.f, 0.f}, acco = {0.f, 0.f, 0.f, 0.f};
    const int c = ns * 16 + c16;
    const u16* wrb = bW1t + (long)c * 128 + quad * 8;
    const u16* wro = oW1t + (long)c * 128 + quad * 8;
    #pragma unroll
    for (int kk = 0; kk < 4; kk++) {
      accb = mfma16(a[kk], ld8(wrb + kk * 32), accb);
      acco = mfma16(a[kk], ld8(wro + kk * 32), acco);
    }
    const float biasb = bb1[c], biaso = ob1[c];
    #pragma unroll
    for (int r = 0; r < 4; r++) {
      float vb = accb[r] + biasb;
      float vo = acco[r] + biaso;
      H1[wave * 16 + quad * 4 + r][c] = f2b(vb > 0.f ? vb : 0.f);
      H3[wave * 16 + quad * 4 + r][c] = f2b(vo > 0.f ? vo : 0.f);
    }
  }
  {
    const long bat = ((long)bx * 64) / N_;
    const float vx0 = vxyz[bat * 3 + 0];
    const float vx1 = vxyz[bat * 3 + 1];
    const float vx2 = vxyz[bat * 3 + 2];
    for (int i = 0; i < 32; i++) {
      const int e = lane + 64 * i;
      const int rr = e >> 7, cc = e & 127;
      const long gr = row0 + rr;
      const float d0 = fabsf(pxyz[gr * 3 + 0] - vx0);
      const float d1 = fabsf(pxyz[gr * 3 + 1] - vx1);
      const float d2 = fabsf(pxyz[gr * 3 + 2] - vx2);
      float h = d0 * dW1[cc] + d1 * dW1[128 + cc] + d2 * dW1[256 + cc] + db1[cc];
      H2[wave * 16 + rr][cc] = f2b(h > 0.f ? h : 0.f);
    }
  }
  __syncthreads();                               // single fence: writes -> reads
  s8 ab[4], ad[4], ao[4];
  #pragma unroll
  for (int kk = 0; kk < 4; kk++) {
    ab[kk] = *reinterpret_cast<const s8*>(&H1[wave * 16 + c16][kk * 32 + quad * 8]);
    ad[kk] = *reinterpret_cast<const s8*>(&H2[wave * 16 + c16][kk * 32 + quad * 8]);
    ao[kk] = *reinterpret_cast<const s8*>(&H3[wave * 16 + c16][kk * 32 + quad * 8]);
  }
  #pragma unroll
  for (int ns = 0; ns < 8; ns++) {
    const int c = ns * 16 + c16;
    f4 acck = {0.f, 0.f, 0.f, 0.f};              // kpv = beta-L2 + delta-L2
    f4 accv = {0.f, 0.f, 0.f, 0.f};              // vt = omega-L2
    const u16* wrb = bW2t + (long)c * 128 + quad * 8;
    const u16* wrd = dW2t + (long)c * 128 + quad * 8;
    const u16* wro = oW2t + (long)c * 128 + quad * 8;
    #pragma unroll
    for (int kk = 0; kk < 4; kk++) {
      acck = mfma16(ab[kk], ld8(wrb + kk * 32), acck);
      acck = mfma16(ad[kk], ld8(wrd + kk * 32), acck);
      accv = mfma16(ao[kk], ld8(wro + kk * 32), accv);
    }
    const float biask = bb2[c] + db2[c];
    const float biasv = ob2[c];
    #pragma unroll
    for (int r = 0; r < 4; r++)
      kpv_out[(row0 + quad * 4 + r) * D_ + c] = f2b(acck[r] + biask);
    {
      const long g = row0 + quad * 4;
      const long bb = g >> 14;
      const long n = g & (N_ - 1);
      us4 pk;
      #pragma unroll
      for (int r = 0; r < 4; r++) pk[r] = f2b(accv[r] + biasv);
      *reinterpret_cast<us4*>(vt_out + bb * (long)128 * N_ + (long)c * N_ + n) = pk;
    }
  }
}

// Pass 1 v2c (r12 verified): m-split x4, raw column sums.
__global__ __launch_bounds__(512, 6) void colsum_v2c(const u16* __restrict__ q,
    const u16* __restrict__ kpv, float* __restrict__ sums) {
  __shared__ char LQ[16384];                     // 64 m x 128 k bf16, swizzled
  const int tid = threadIdx.x;
  const int wave = tid >> 6, lane = tid & 63;
  const int c16 = lane & 15, quad = lane >> 4;
  const int mh = blockIdx.x & 3;
  const int nb = ((blockIdx.x >> 2) & 127) * 128 + wave * 16;
  const int b = blockIdx.x >> 9;
  const int rsub = lane >> 4, ch = lane & 15;

  s8 ak[4];
  {
    const u16* kr = kpv + ((long)b * N_ + nb + c16) * D_ + quad * 8;
    #pragma unroll
    for (int kk = 0; kk < 4; kk++) ak[kk] = ld8(kr + kk * 32);
  }
  f4 sum = {0.f, 0.f, 0.f, 0.f};
  const u16* qb = q + (long)b * M_ * D_ + (long)mh * (M_ / 4) * D_;

  for (int m0 = 0; m0 < M_ / 4; m0 += 64) {
    s8 t0 = ld8(qb + (long)(m0 + wave * 8 + rsub) * D_ + ch * 8);
    s8 t1 = ld8(qb + (long)(m0 + wave * 8 + 4 + rsub) * D_ + ch * 8);
    *reinterpret_cast<s8*>(LQ + swz(wave * 8 + rsub, ch * 16)) = t0;
    *reinterpret_cast<s8*>(LQ + swz(wave * 8 + 4 + rsub, ch * 16)) = t1;
    __syncthreads();
    #pragma unroll
    for (int ms = 0; ms < 4; ms++) {
      f4 st = {0.f, 0.f, 0.f, 0.f};
      #pragma unroll
      for (int kk = 0; kk < 4; kk++) {
        s8 bq = *reinterpret_cast<const s8*>(LQ + swz(ms * 16 + c16, kk * 64 + quad * 16));
        st = mfma16(ak[kk], bq, st);
      }
      #pragma unroll
      for (int r = 0; r < 4; r++) sum[r] += exp2f(st[r] * CS);
    }
    __syncthreads();
  }
  #pragma unroll
  for (int mask = 1; mask < 16; mask <<= 1) {
    #pragma unroll
    for (int r = 0; r < 4; r++) sum[r] += __shfl_xor(sum[r], mask, 64);
  }
  if (c16 == 0)
    *reinterpret_cast<f4*>(sums + (long)mh * (B_ * N_) + (long)b * N_ + nb + quad * 4) = sum;
}

// l2ic = -log2(sum of the four m-split partials): folded into exp2 in attn.
__global__ __launch_bounds__(256) void recip_k(const float* __restrict__ sums,
                                               float* __restrict__ l2ic) {
  const int i = blockIdx.x * 256 + threadIdx.x;  // 0 .. B*N-1
  const float s = sums[i] + sums[B_ * N_ + i] + sums[2 * B_ * N_ + i]
                + sums[3 * B_ * N_ + i];
  l2ic[i] = -log2f(s);
}

// Pass 2a v7 (r12 verified, 139 us): P = exp2(s*CS + l2ic).
// NOTE: do NOT extend cross-barrier liveness here (r9 spill: 14x HBM fetch).
__global__ __launch_bounds__(256, 4) void attn_v7(const u16* __restrict__ q,
    const u16* __restrict__ kpv, const u16* __restrict__ vt,
    const float* __restrict__ l2ic, float* __restrict__ part,
    int lgns, int nslice) {
  __shared__ char LK[16384];
  __shared__ char LP[8192];
  const int tid = threadIdx.x;
  const int wave = tid >> 6, lane = tid & 63;
  const int l31 = lane & 31, hi = lane >> 5;
  const int bid = blockIdx.x;                    // b x mb(64) x ns
  const int ns = bid & ((1 << lgns) - 1);
  const int mb = (bid >> lgns) & 63;
  const int b = bid >> (lgns + 6);
  const int nt = wave & 1, mt = wave >> 1;       // S^T tile: 32n x 32m
  const int m_base = mb * 64;
  const int n_begin = ns * nslice;
  const int rsub = lane >> 4, ch = lane & 15;    // staging roles

  const u16* kpb = kpv + (long)b * N_ * D_;
  const u16* vtb = vt + (long)b * (long)D_ * N_;
  const float* l2b = l2ic + (long)b * N_;

  s8 bq[8];                                      // Q B-frags: 8 ksteps (K=128)
  {
    const u16* qr = q + ((long)b * M_ + m_base + mt * 32 + l31) * D_ + hi * 8;
    #pragma unroll
    for (int kk = 0; kk < 8; kk++) bq[kk] = ld8(qr + kk * 16);
  }
  f16v acc[2];                                   // O: 2 m-tiles x wave's 32 d
  #pragma unroll
  for (int i = 0; i < 2; i++)
    #pragma unroll
    for (int r = 0; r < 16; r++) acc[i][r] = 0.f;

  // preload first KPV chunk into regs
  s8 tmp[4];
  #pragma unroll
  for (int i = 0; i < 4; i++)
    tmp[i] = ld8(kpb + (long)(n_begin + wave * 16 + i * 4 + rsub) * D_ + ch * 8);

  for (int n0 = n_begin; n0 < n_begin + nslice; n0 += 64) {
    // write staged KPV(i) -> LK
    #pragma unroll
    for (int i = 0; i < 4; i++)
      *reinterpret_cast<s8*>(LK + swz(wave * 16 + i * 4 + rsub, ch * 16)) = tmp[i];
    // prefetch KPV(i+1)
    {
      int nn = n0 + 64;
      if (nn >= n_begin + nslice) nn = n_begin;  // last iter: dummy (unused)
      #pragma unroll
      for (int i = 0; i < 4; i++)
        tmp[i] = ld8(kpb + (long)(nn + wave * 16 + i * 4 + rsub) * D_ + ch * 8);
    }
    __syncthreads();                             // LK ready; LP safe (PV(i-1) done)
    // ---- S^T: wave tile 32n(nt) x 32m(mt), K=128 ----
    {
      f16v st;
      #pragma unroll
      for (int r = 0; r < 16; r++) st[r] = 0.f;
      #pragma unroll
      for (int kk = 0; kk < 8; kk++) {
        s8 aK = *reinterpret_cast<const s8*>(
            LK + swz(nt * 32 + l31, kk * 32 + hi * 16));
        st = mfma32(aK, bq[kk], st);
      }
      // C: col=m (l31), row n = nt*32 + 8g + 4hi + r  (reg = g*4+r)
      #pragma unroll
      for (int g = 0; g < 4; g++) {
        const f4 l2 = *reinterpret_cast<const f4*>(l2b + n0 + nt * 32 + 8 * g + 4 * hi);
        us4 pk;
        #pragma unroll
        for (int r = 0; r < 4; r++)
          pk[r] = (u16)(__float_as_uint(exp2f(fmaf(st[g * 4 + r], CS, l2[r]))) >> 16);
        // LP: granule (4nt+g), row m = mt*32+l31, byte 8*hi
        *reinterpret_cast<us4*>(LP + (4 * nt + g) * 1024 + (mt * 32 + l31) * 16 + 8 * hi) = pk;
      }
    }
    __syncthreads();                             // LP ready; LK(i) reads done
    // ---- PV: wave owns 32 d (wave*32), both m-tiles, K=64 ----
    #pragma unroll
    for (int kk = 0; kk < 4; kk++) {
      s8 bv = ld8(vtb + (long)(wave * 32 + l31) * N_ + n0 + kk * 16 + hi * 8);
      #pragma unroll
      for (int i = 0; i < 2; i++) {
        s8 ap = *reinterpret_cast<const s8*>(
            LP + (2 * kk + hi) * 1024 + (i * 32 + l31) * 16);
        acc[i] = mfma32(ap, bv, acc[i]);
      }
    }
  }
  // store partial tile [64m][128d] f32; C: col=d, row m=(reg&3)+8*(reg>>2)+4*hi
  float* pt = part + (long)bid * 64 * 128;
  #pragma unroll
  for (int i = 0; i < 2; i++)
    #pragma unroll
    for (int g = 0; g < 4; g++)
      #pragma unroll
      for (int r = 0; r < 4; r++)
        pt[(i * 32 + g * 8 + 4 * hi + r) * 128 + wave * 32 + l31] = acc[i][g * 4 + r];
}

// Pass 2b: out = sum_ns partial + vfeat  (f32 out)
__global__ __launch_bounds__(256) void attn_reduce(const float* __restrict__ part,
    const float* __restrict__ vfeat, float* __restrict__ out, int nsplit) {
  const int g4 = blockIdx.x * 256 + threadIdx.x;     // 0 .. B*M*D/4-1
  const int b = g4 >> 17;                            // M*D/4 = 131072
  const int rem = g4 & 131071;
  const int m = rem >> 5;
  const int d4 = rem & 31;
  const int mb = m >> 6, mr = m & 63;
  const long base = ((long)(b * 64 + mb) * nsplit) * 8192 + mr * 128 + d4 * 4;
  f4 s = *reinterpret_cast<const f4*>(vfeat + (long)g4 * 4);
  for (int ns = 0; ns < nsplit; ns++)
    s += *reinterpret_cast<const f4*>(part + base + ns * 8192);
  *reinterpret_cast<f4*>(out + (long)g4 * 4) = s;
}

extern "C" void kernel_launch(void* const* d_in, const int* in_sizes, int n_in,
                              void* d_out, int out_size, void* d_ws, size_t ws_size,
                              hipStream_t stream) {
  const float* p_xyz  = (const float*)d_in[0];
  const float* v_xyz  = (const float*)d_in[1];
  const float* p_feat = (const float*)d_in[2];
  const float* v_feat = (const float*)d_in[3];
  const float* aW1 = (const float*)d_in[4],  *ab1 = (const float*)d_in[5];
  const float* aW2 = (const float*)d_in[6],  *ab2 = (const float*)d_in[7];
  const float* bW1 = (const float*)d_in[8],  *bb1 = (const float*)d_in[9];
  const float* bW2 = (const float*)d_in[10], *bb2 = (const float*)d_in[11];
  const float* oW1 = (const float*)d_in[12], *ob1 = (const float*)d_in[13];
  const float* oW2 = (const float*)d_in[14], *ob2 = (const float*)d_in[15];
  const float* dW1 = (const float*)d_in[16], *db1 = (const float*)d_in[17];
  const float* dW2 = (const float*)d_in[18], *db2 = (const float*)d_in[19];

  char* ws = (char*)d_ws;
  u16* wt    = (u16*)ws;                               // 7 * 16384 bf16 elems
  u16* aW1t  = wt + 0 * 16384;
  u16* aW2t  = wt + 1 * 16384;
  u16* bW1t  = wt + 2 * 16384;
  u16* bW2t  = wt + 3 * 16384;
  u16* oW1t  = wt + 4 * 16384;
  u16* oW2t  = wt + 5 * 16384;
  u16* dW2t  = wt + 6 * 16384;
  u16* qbuf  = (u16*)(ws + 262144);                    // B*M*D bf16 = 2 MB
  u16* kpvb  = (u16*)(ws + 2359296);                   // B*N*D bf16 = 8 MB
  u16* vtb   = (u16*)(ws + 10747904);                  // Vt = 8 MB
  float* invb = (float*)(ws + 19136512);               // B*N f32 = 128 KB (l2ic)
  float* partb = (float*)(ws + 19267584);              // nsplit * 4 MB
  float* sums  = partb;                                // 512 KB, consumed pre-attn

  const size_t part_off = 19267584;
  int lgns = (ws_size >= part_off + (size_t)8 * B_ * M_ * D_ * 4) ? 3 : 2;
  const int nsplit = 1 << lgns;                        // capped at 8 (16 regressed)
  const int nslice = N_ / nsplit;

  wtrans<<<dim3(112), dim3(256), 0, stream>>>(aW1, aW2, bW1, bW2, oW1, oW2, dW2, wt);
  mlps<<<dim3(256 + (B_ * N_) / 64), dim3(256), 0, stream>>>(
      v_feat, aW1t, ab1, aW2t, ab2, qbuf,
      p_feat, p_xyz, v_xyz, bW1t, bb1, bW2t, bb2, dW1, db1, dW2t, db2,
      oW1t, ob1, oW2t, ob2, kpvb, vtb);
  colsum_v2c<<<dim3(B_ * 128 * 4), dim3(512), 0, stream>>>(qbuf, kpvb, sums);
  recip_k<<<dim3((B_ * N_) / 256), dim3(256), 0, stream>>>(sums, invb);
  attn_v7<<<dim3(B_ * 64 * nsplit), dim3(256), 0, stream>>>(qbuf, kpvb, vtb, invb, partb,
                                                            lgns, nslice);
  attn_reduce<<<dim3((B_ * M_ * D_ / 4) / 256), dim3(256), 0, stream>>>(partb, v_feat,
                                                                        (float*)d_out,
                                                                        nsplit);
}